// Round 1
// baseline (1040.929 us; speedup 1.0000x reference)
//
#include <hip/hip_runtime.h>
#include <math.h>

// Problem dims (fixed by reference setup_inputs)
#define BB   128
#define NN   512
#define DIN  64
#define HH   256
#define DOUT 64
#define BNR  (BB * NN)          // 65536 rows

// Haar/db1 'zero' DWT patterns for levels 1..3, FULL_LEN=8 (precomputed from reference)
__constant__ float PAT[3][8] = {
    {0.70710678f, 0.70710678f, 0.f, 0.f, 0.f, 0.f, 0.f, 0.f},
    {0.5f,        0.70710678f, 0.f, 0.5f, 0.f, 0.f, 0.f, 0.f},
    {0.35355339f, 0.70710678f, 0.f, 0.f, 0.f, 0.5f, 0.f, 0.35355339f}
};

// ---------------------------------------------------------------------------
// Generic tiled fp32 GEMM: C[b] = A[b] @ W[b] + bias + resid[b]
// A: (M x K) row-major, W: (K x Nc) row-major, C: (M x Nc) row-major.
// Batched via blockIdx.z with per-batch element strides sA/sW/sC (0 = shared).
// resid (optional) has the same layout/stride as C; in-place C==resid is safe
// (each output element read+written exactly once by its owning thread).
// Tiles: 64x64, BK=16; 256 threads; 4x4 micro-tile per thread.
// Requires: M%64==0, Nc%64==0, K%16==0 (all shapes here satisfy this).
// ---------------------------------------------------------------------------
__global__ __launch_bounds__(256) void gemm_k(
    const float* __restrict__ A, const float* __restrict__ W,
    const float* __restrict__ bias, const float* __restrict__ resid,
    float* __restrict__ C, int M, int K, int Nc,
    long sA, long sW, long sC)
{
    const long bz = blockIdx.z;
    A += bz * sA;
    W += bz * sW;
    C += bz * sC;
    const float* Rp = resid ? resid + bz * sC : nullptr;

    const int m0 = blockIdx.y * 64;
    const int n0 = blockIdx.x * 64;
    const int tid = threadIdx.x;
    const int tx = tid & 15;        // 0..15 -> 4 output cols each
    const int ty = tid >> 4;        // 0..15 -> 4 output rows each

    __shared__ float As[64][17];    // [m][k], +1 pad
    __shared__ float Ws[16][64];    // [k][n]

    float acc[4][4] = {};

    const int lm = tid >> 2;            // 0..63   A-tile row
    const int lk = (tid & 3) << 2;      // 0,4,8,12 A-tile col (float4)
    const int wk = tid >> 4;            // 0..15   W-tile row
    const int wn = (tid & 15) << 2;     // 0..60   W-tile col (float4)

    for (int k0 = 0; k0 < K; k0 += 16) {
        float4 av = *reinterpret_cast<const float4*>(A + (long)(m0 + lm) * K + (k0 + lk));
        As[lm][lk + 0] = av.x;
        As[lm][lk + 1] = av.y;
        As[lm][lk + 2] = av.z;
        As[lm][lk + 3] = av.w;
        float4 wv = *reinterpret_cast<const float4*>(W + (long)(k0 + wk) * Nc + (n0 + wn));
        *reinterpret_cast<float4*>(&Ws[wk][wn]) = wv;
        __syncthreads();

        #pragma unroll
        for (int kk = 0; kk < 16; ++kk) {
            float a0 = As[ty * 4 + 0][kk];
            float a1 = As[ty * 4 + 1][kk];
            float a2 = As[ty * 4 + 2][kk];
            float a3 = As[ty * 4 + 3][kk];
            float4 w4 = *reinterpret_cast<float4*>(&Ws[kk][tx * 4]);
            acc[0][0] += a0 * w4.x; acc[0][1] += a0 * w4.y; acc[0][2] += a0 * w4.z; acc[0][3] += a0 * w4.w;
            acc[1][0] += a1 * w4.x; acc[1][1] += a1 * w4.y; acc[1][2] += a1 * w4.z; acc[1][3] += a1 * w4.w;
            acc[2][0] += a2 * w4.x; acc[2][1] += a2 * w4.y; acc[2][2] += a2 * w4.z; acc[2][3] += a2 * w4.w;
            acc[3][0] += a3 * w4.x; acc[3][1] += a3 * w4.y; acc[3][2] += a3 * w4.z; acc[3][3] += a3 * w4.w;
        }
        __syncthreads();
    }

    const int n = n0 + tx * 4;
    float4 b4 = make_float4(0.f, 0.f, 0.f, 0.f);
    if (bias) b4 = *reinterpret_cast<const float4*>(bias + n);
    #pragma unroll
    for (int i = 0; i < 4; ++i) {
        const long m = m0 + ty * 4 + i;
        float4 v;
        v.x = acc[i][0] + b4.x;
        v.y = acc[i][1] + b4.y;
        v.z = acc[i][2] + b4.z;
        v.w = acc[i][3] + b4.w;
        if (Rp) {
            float4 r = *reinterpret_cast<const float4*>(Rp + m * Nc + n);
            v.x += r.x; v.y += r.y; v.z += r.z; v.w += r.w;
        }
        *reinterpret_cast<float4*>(C + m * Nc + n) = v;
    }
}

// ---------------------------------------------------------------------------
// _mix: stage 1 — per-block partial sums of (h-r)^2 (deterministic, no atomics)
// ---------------------------------------------------------------------------
__global__ __launch_bounds__(256) void diff_partial_k(
    const float* __restrict__ h, const float* __restrict__ r,
    float* __restrict__ partial, long n4)
{
    long gid = (long)blockIdx.x * 256 + threadIdx.x;
    long stride = (long)gridDim.x * 256;
    float s = 0.f;
    for (long i = gid; i < n4; i += stride) {
        float4 a = reinterpret_cast<const float4*>(h)[i];
        float4 b = reinterpret_cast<const float4*>(r)[i];
        float dx = a.x - b.x, dy = a.y - b.y, dz = a.z - b.z, dw = a.w - b.w;
        s += dx * dx + dy * dy + dz * dz + dw * dw;
    }
    __shared__ float sm[256];
    sm[threadIdx.x] = s;
    __syncthreads();
    for (int o = 128; o > 0; o >>= 1) {
        if (threadIdx.x < o) sm[threadIdx.x] += sm[threadIdx.x + o];
        __syncthreads();
    }
    if (threadIdx.x == 0) partial[blockIdx.x] = sm[0];
}

// stage 2 — sum partials, th = sigmoid(mean)
__global__ __launch_bounds__(256) void diff_final_k(
    const float* __restrict__ partial, int np, float* __restrict__ th_out, float inv_n)
{
    float s = 0.f;
    for (int i = threadIdx.x; i < np; i += 256) s += partial[i];
    __shared__ float sm[256];
    sm[threadIdx.x] = s;
    __syncthreads();
    for (int o = 128; o > 0; o >>= 1) {
        if (threadIdx.x < o) sm[threadIdx.x] += sm[threadIdx.x + o];
        __syncthreads();
    }
    if (threadIdx.x == 0) {
        float d = sm[0] * inv_n;
        th_out[0] = 1.f / (1.f + expf(-d));
    }
}

// stage 3 — h = th*h + (1-th)*r   (in place on h)
__global__ __launch_bounds__(256) void mix_apply_k(
    float* __restrict__ h, const float* __restrict__ r,
    const float* __restrict__ th_p, long n4)
{
    const float th = th_p[0];
    const float om = 1.f - th;
    long gid = (long)blockIdx.x * 256 + threadIdx.x;
    long stride = (long)gridDim.x * 256;
    for (long i = gid; i < n4; i += stride) {
        float4 a = reinterpret_cast<float4*>(h)[i];
        float4 b = reinterpret_cast<const float4*>(r)[i];
        a.x = th * a.x + om * b.x;
        a.y = th * a.y + om * b.y;
        a.z = th * a.z + om * b.z;
        a.w = th * a.w + om * b.w;
        reinterpret_cast<float4*>(h)[i] = a;
    }
}

// ---------------------------------------------------------------------------
// wavelet coeff: per feature f, l* = argmax_l(logits[l]+gumb[f][l]) (first max,
// matching jnp.argmax); coeff[f] = dot(Wnl[f], P[l*]).
// ---------------------------------------------------------------------------
__global__ void coeff_k(const float* __restrict__ logits, const float* __restrict__ gumb,
                        const float* __restrict__ Wnl, float* __restrict__ coeff)
{
    int f = threadIdx.x;   // 256 features
    float l0 = logits[0] + gumb[f * 3 + 0];
    float l1 = logits[1] + gumb[f * 3 + 1];
    float l2 = logits[2] + gumb[f * 3 + 2];
    int bl = 0;
    float bv = l0;
    if (l1 > bv) { bv = l1; bl = 1; }
    if (l2 > bv) { bv = l2; bl = 2; }
    float s = 0.f;
    #pragma unroll
    for (int t = 0; t < 8; ++t) s += Wnl[f * 8 + t] * PAT[bl][t];
    coeff[f] = s;
}

// agg = h * coeff[f] + bnl[f]  (per-feature scale+bias), F multiple of 4
__global__ __launch_bounds__(256) void agg_k(
    const float* __restrict__ h, const float* __restrict__ coeff,
    const float* __restrict__ bnl, float* __restrict__ out, long n4, int F4)
{
    long gid = (long)blockIdx.x * 256 + threadIdx.x;
    long stride = (long)gridDim.x * 256;
    for (long i = gid; i < n4; i += stride) {
        int f4 = (int)(i % F4);
        float4 c = reinterpret_cast<const float4*>(coeff)[f4];
        float4 b = reinterpret_cast<const float4*>(bnl)[f4];
        float4 v = reinterpret_cast<const float4*>(h)[i];
        v.x = v.x * c.x + b.x;
        v.y = v.y * c.y + b.y;
        v.z = v.z * c.z + b.z;
        v.w = v.w * c.w + b.w;
        reinterpret_cast<float4*>(out)[i] = v;
    }
}

// ---------------------------------------------------------------------------
extern "C" void kernel_launch(void* const* d_in, const int* in_sizes, int n_in,
                              void* d_out, int out_size, void* d_ws, size_t ws_size,
                              hipStream_t stream)
{
    const float* x       = (const float*)d_in[0];
    const float* adj     = (const float*)d_in[1];
    const float* Wres    = (const float*)d_in[2];
    const float* bres    = (const float*)d_in[3];
    const float* Wg0     = (const float*)d_in[4];
    const float* bg0     = (const float*)d_in[5];
    const float* Wrg0    = (const float*)d_in[6];
    const float* brg0    = (const float*)d_in[7];
    const float* logits0 = (const float*)d_in[8];
    const float* gumb0   = (const float*)d_in[9];
    const float* Wnl0    = (const float*)d_in[10];
    const float* bnl0    = (const float*)d_in[11];
    const float* Wwo0    = (const float*)d_in[12];
    const float* bwo0    = (const float*)d_in[13];
    const float* Wrw0    = (const float*)d_in[14];
    const float* brw0    = (const float*)d_in[15];
    const float* Wg1     = (const float*)d_in[16];
    const float* bg1     = (const float*)d_in[17];
    const float* Wrg1    = (const float*)d_in[18];
    const float* brg1    = (const float*)d_in[19];
    const float* logits1 = (const float*)d_in[20];
    const float* gumb1   = (const float*)d_in[21];
    const float* Wnl1    = (const float*)d_in[22];
    const float* bnl1    = (const float*)d_in[23];
    const float* Wwo1    = (const float*)d_in[24];
    const float* bwo1    = (const float*)d_in[25];
    const float* Wrw1    = (const float*)d_in[26];
    const float* brw1    = (const float*)d_in[27];

    float* out = (float*)d_out;
    float* ws  = (float*)d_ws;

    // workspace layout (floats):
    //   R    : BN x 64      (res = x@Wres+bres, live whole call)
    //   BufA : BN x 256
    //   BufB : BN x 256
    //   partial[2048], th[4], c0[256], c1[256]
    // total ~151 MB
    float* R       = ws;
    float* BufA    = R + (long)BNR * DOUT;
    float* BufB    = BufA + (long)BNR * HH;
    float* partial = BufB + (long)BNR * HH;
    float* th_s    = partial + 2048;
    float* c0      = th_s + 4;
    float* c1      = c0 + 256;

    const dim3 blk(256);

    auto gemm = [&](const float* A, const float* W, const float* bias, const float* resid,
                    float* C, int M, int K, int Nc, int batches, long sA, long sW, long sC) {
        dim3 grid(Nc / 64, M / 64, batches);
        hipLaunchKernelGGL(gemm_k, grid, blk, 0, stream, A, W, bias, resid, C, M, K, Nc, sA, sW, sC);
    };
    auto mix = [&](float* h, const float* r, long n) {
        long n4 = n / 4;
        hipLaunchKernelGGL(diff_partial_k, dim3(2048), blk, 0, stream, h, r, partial, n4);
        hipLaunchKernelGGL(diff_final_k, dim3(1), blk, 0, stream, partial, 2048, th_s, 1.0f / (float)n);
        hipLaunchKernelGGL(mix_apply_k, dim3(2048), blk, 0, stream, h, r, th_s, n4);
    };

    // res = x @ Wres + bres
    gemm(x, Wres, bres, nullptr, R, BNR, DIN, DOUT, 1, 0, 0, 0);

    // ---- layer 0 ----
    // T0 = adj @ x  (batched over B; adj shared)
    gemm(adj, x, nullptr, nullptr, BufB, NN, NN, DIN, BB, 0, (long)NN * DIN, (long)NN * DIN);
    // xg = T0 @ Wg0 + bg0
    gemm(BufB, Wg0, bg0, nullptr, BufA, BNR, DIN, HH, 1, 0, 0, 0);
    // rp = res @ Wrg0 + brg0
    gemm(R, Wrg0, brg0, nullptr, BufB, BNR, DIN, HH, 1, 0, 0, 0);
    // xg = mix(xg, rp)
    mix(BufA, BufB, (long)BNR * HH);
    // wavelet 0: coeff, agg, linear_out (+xg residual)
    hipLaunchKernelGGL(coeff_k, dim3(1), dim3(256), 0, stream, logits0, gumb0, Wnl0, c0);
    hipLaunchKernelGGL(agg_k, dim3(2048), blk, 0, stream, BufA, c0, bnl0, BufB, (long)BNR * HH / 4, HH / 4);
    gemm(BufB, Wwo0, bwo0, BufA, BufA, BNR, HH, HH, 1, 0, 0, 0);   // xw = agg@Wwo0+bwo0+xg
    // rp = res @ Wrw0 + brw0 ; xw = mix(xw, rp)
    gemm(R, Wrw0, brw0, nullptr, BufB, BNR, DIN, HH, 1, 0, 0, 0);
    mix(BufA, BufB, (long)BNR * HH);

    // ---- layer 1 ----
    // T1 = adj @ xw (batched)
    gemm(adj, BufA, nullptr, nullptr, BufB, NN, NN, HH, BB, 0, (long)NN * HH, (long)NN * HH);
    // xg1 = T1 @ Wg1 + bg1 + xw
    gemm(BufB, Wg1, bg1, BufA, BufA, BNR, HH, HH, 1, 0, 0, 0);
    // rp = res @ Wrg1 + brg1 ; xg1 = mix(xg1, rp)
    gemm(R, Wrg1, brg1, nullptr, BufB, BNR, DIN, HH, 1, 0, 0, 0);
    mix(BufA, BufB, (long)BNR * HH);
    // wavelet 1 (256 -> 64, no residual add)
    hipLaunchKernelGGL(coeff_k, dim3(1), dim3(256), 0, stream, logits1, gumb1, Wnl1, c1);
    hipLaunchKernelGGL(agg_k, dim3(2048), blk, 0, stream, BufA, c1, bnl1, BufB, (long)BNR * HH / 4, HH / 4);
    gemm(BufB, Wwo1, bwo1, nullptr, out, BNR, HH, DOUT, 1, 0, 0, 0);
    // rp = res @ Wrw1 + brw1 ; out = mix(out, rp)   (BufA free now, reuse)
    gemm(R, Wrw1, brw1, nullptr, BufA, BNR, DIN, DOUT, 1, 0, 0, 0);
    mix(out, BufA, (long)BNR * DOUT);
}

// Round 2
// 525.121 us; speedup vs baseline: 1.9823x; 1.9823x over previous
//
#include <hip/hip_runtime.h>
#include <hip/hip_bf16.h>
#include <math.h>

#define BB   128
#define NN   512
#define DIN  64
#define HH   256
#define DOUT 64
#define BNR  (BB * NN)          // 65536 rows

typedef float  f32x4  __attribute__((ext_vector_type(4)));
typedef __bf16 bf16x8 __attribute__((ext_vector_type(8)));

#define GLP(p)  ((const __attribute__((address_space(1))) void*)(p))
#define LDSP(p) ((__attribute__((address_space(3))) void*)(p))

// Haar/db1 'zero' DWT patterns, levels 1..3, FULL_LEN=8
__constant__ float PAT[3][8] = {
    {0.70710678f, 0.70710678f, 0.f, 0.f, 0.f, 0.f, 0.f, 0.f},
    {0.5f,        0.70710678f, 0.f, 0.5f, 0.f, 0.f, 0.f, 0.f},
    {0.35355339f, 0.70710678f, 0.f, 0.f, 0.f, 0.5f, 0.f, 0.35355339f}
};

__device__ __forceinline__ unsigned short f2bfu(float x) {
    __hip_bfloat16 b = __float2bfloat16(x);
    unsigned short u;
    __builtin_memcpy(&u, &b, 2);
    return u;
}

// ---------------------------------------------------------------------------
// fp32 -> bf16 elementwise convert (vectorized)
// ---------------------------------------------------------------------------
__global__ __launch_bounds__(256) void cvt_k(const float* __restrict__ in,
                                             __hip_bfloat16* __restrict__ out, long n4)
{
    long gid = (long)blockIdx.x * 256 + threadIdx.x;
    long stride = (long)gridDim.x * 256;
    for (long i = gid; i < n4; i += stride) {
        float4 v = reinterpret_cast<const float4*>(in)[i];
        ushort4 u;
        u.x = f2bfu(v.x); u.y = f2bfu(v.y); u.z = f2bfu(v.z); u.w = f2bfu(v.w);
        reinterpret_cast<ushort4*>(out)[i] = u;
    }
}

// ---------------------------------------------------------------------------
// batched transpose-convert: in (bz,R,C) fp32 row-major -> out (bz,C,R) bf16
// 64x64 tiles, R%64==0, C%64==0
// ---------------------------------------------------------------------------
__device__ __forceinline__ void tcvt_body(const float* __restrict__ in,
                                          __hip_bfloat16* __restrict__ out,
                                          int R, int C, int r0, int c0)
{
    __shared__ float t[64][65];
    int tr = threadIdx.x >> 6;      // 0..3
    int tc = threadIdx.x & 63;      // 0..63
    #pragma unroll
    for (int i = 0; i < 16; ++i) {
        int r = i * 4 + tr;
        t[r][tc] = in[(long)(r0 + r) * C + c0 + tc];
    }
    __syncthreads();
    #pragma unroll
    for (int i = 0; i < 16; ++i) {
        int r = i * 4 + tr;
        out[(long)(c0 + r) * R + r0 + tc] = __float2bfloat16(t[tc][r]);
    }
}

__global__ __launch_bounds__(256) void tcvt_k(const float* __restrict__ in,
                                              __hip_bfloat16* __restrict__ out,
                                              int R, int C, long sz)
{
    long base = (long)blockIdx.z * sz;
    tcvt_body(in + base, out + base, R, C, blockIdx.y * 64, blockIdx.x * 64);
}

// fused weight transposes (9 weights, one launch)
struct WTArgs {
    const float* src[9];
    __hip_bfloat16* dst[9];
    int R[9], C[9];
};
__global__ __launch_bounds__(256) void tcvt_w_k(WTArgs a)
{
    int wgt = blockIdx.y;
    int R = a.R[wgt], C = a.C[wgt];
    int tilesX = C >> 6;
    int tiles = (R >> 6) * tilesX;
    int t = blockIdx.x;
    if (t >= tiles) return;
    tcvt_body(a.src[wgt], a.dst[wgt], R, C, (t / tilesX) * 64, (t % tilesX) * 64);
}

// ---------------------------------------------------------------------------
// MFMA bf16 GEMM, B-transposed input:
//   C[bz](M,N) = A[bz](M,K) @ B  with Bt[bz](N,K) row-major bf16
// Epilogue: + bias[col] (+ resid fp32, same layout as C); out fp32 (Cf) or
// bf16 (Cb). BK=64. LDS rows 128B, XOR-swizzled (slot16 ^= row&7) with the
// inverse swizzle applied to the per-lane global source of global_load_lds.
// 4 waves (2x2). Wave tile = (FM*16) x (FN*16); BM=32*FM, BN=32*FN.
// Requires M%BM==0, N%BN==0, K%64==0.
// ---------------------------------------------------------------------------
template<int BM, int BN, int FM, int FN>
__global__ __launch_bounds__(256) void gemm_bt_k(
    const __hip_bfloat16* __restrict__ A, const __hip_bfloat16* __restrict__ Bt,
    const float* __restrict__ bias, const float* __restrict__ resid,
    float* __restrict__ Cf, __hip_bfloat16* __restrict__ Cb,
    int M, int N, int K, long sA, long sB, long sC)
{
    __shared__ __attribute__((aligned(128))) char lds[(BM + BN) * 128];
    char* AsB = lds;
    char* BsB = lds + BM * 128;

    const long bz = blockIdx.z;
    const __hip_bfloat16* Ab = A + bz * sA;
    const __hip_bfloat16* Bb = Bt + bz * sB;

    const int m0 = blockIdx.y * BM;
    const int n0 = blockIdx.x * BN;
    const int tid  = threadIdx.x;
    const int wave = tid >> 6;
    const int lane = tid & 63;
    const int wm = wave >> 1, wn = wave & 1;

    const int NCH = (BM + BN) / 32;      // staging chunks per wave
    const int lr = lane >> 3;            // row within 8-row chunk
    const int ls = lane & 7;             // 16B slot within 128B row

    f32x4 acc[FM][FN];
    #pragma unroll
    for (int i = 0; i < FM; ++i)
        #pragma unroll
        for (int j = 0; j < FN; ++j)
            acc[i][j] = (f32x4){0.f, 0.f, 0.f, 0.f};

    for (int k0 = 0; k0 < K; k0 += 64) {
        #pragma unroll
        for (int cc = 0; cc < NCH; ++cc) {
            int c = wave * NCH + cc;
            const __hip_bfloat16* src;
            char* ldsb;
            if (c < BM / 8) {
                int r = c * 8 + lr;
                ldsb = AsB + c * 1024;
                src = Ab + ((long)(m0 + r) * K + k0 + ((ls ^ (r & 7)) << 3));
            } else {
                int c2 = c - BM / 8;
                int r = c2 * 8 + lr;
                ldsb = BsB + c2 * 1024;
                src = Bb + ((long)(n0 + r) * K + k0 + ((ls ^ (r & 7)) << 3));
            }
            __builtin_amdgcn_global_load_lds(GLP(src), LDSP(ldsb), 16, 0, 0);
        }
        __syncthreads();

        #pragma unroll
        for (int ksl = 0; ksl < 2; ++ksl) {
            bf16x8 af[FM], bfr[FN];
            #pragma unroll
            for (int i = 0; i < FM; ++i) {
                int row = wm * (FM * 16) + i * 16 + (lane & 15);
                int off = (ksl * 64 + ((lane >> 4) << 4)) ^ ((row & 7) << 4);
                af[i] = *reinterpret_cast<const bf16x8*>(AsB + row * 128 + off);
            }
            #pragma unroll
            for (int j = 0; j < FN; ++j) {
                int row = wn * (FN * 16) + j * 16 + (lane & 15);
                int off = (ksl * 64 + ((lane >> 4) << 4)) ^ ((row & 7) << 4);
                bfr[j] = *reinterpret_cast<const bf16x8*>(BsB + row * 128 + off);
            }
            #pragma unroll
            for (int i = 0; i < FM; ++i)
                #pragma unroll
                for (int j = 0; j < FN; ++j)
                    acc[i][j] = __builtin_amdgcn_mfma_f32_16x16x32_bf16(
                        af[i], bfr[j], acc[i][j], 0, 0, 0);
        }
        __syncthreads();
    }

    // epilogue: D col = lane&15, row = (lane>>4)*4 + r (HW-verified layout)
    const int lc  = lane & 15;
    const int lr4 = (lane >> 4) << 2;
    #pragma unroll
    for (int j = 0; j < FN; ++j) {
        int col = n0 + wn * (FN * 16) + j * 16 + lc;
        float bv = bias ? bias[col] : 0.0f;
        #pragma unroll
        for (int i = 0; i < FM; ++i) {
            int row0 = m0 + wm * (FM * 16) + i * 16 + lr4;
            #pragma unroll
            for (int r = 0; r < 4; ++r) {
                long idx = bz * sC + (long)(row0 + r) * N + col;
                float v = acc[i][j][r] + bv;
                if (resid) v += resid[idx];
                if (Cf) Cf[idx] = v;
                else    Cb[idx] = __float2bfloat16(v);
            }
        }
    }
}

// ---------------------------------------------------------------------------
// _mix pieces (fp32, unchanged from round 1)
// ---------------------------------------------------------------------------
__global__ __launch_bounds__(256) void diff_partial_k(
    const float* __restrict__ h, const float* __restrict__ r,
    float* __restrict__ partial, long n4)
{
    long gid = (long)blockIdx.x * 256 + threadIdx.x;
    long stride = (long)gridDim.x * 256;
    float s = 0.f;
    for (long i = gid; i < n4; i += stride) {
        float4 a = reinterpret_cast<const float4*>(h)[i];
        float4 b = reinterpret_cast<const float4*>(r)[i];
        float dx = a.x - b.x, dy = a.y - b.y, dz = a.z - b.z, dw = a.w - b.w;
        s += dx * dx + dy * dy + dz * dz + dw * dw;
    }
    __shared__ float sm[256];
    sm[threadIdx.x] = s;
    __syncthreads();
    for (int o = 128; o > 0; o >>= 1) {
        if (threadIdx.x < o) sm[threadIdx.x] += sm[threadIdx.x + o];
        __syncthreads();
    }
    if (threadIdx.x == 0) partial[blockIdx.x] = sm[0];
}

__global__ __launch_bounds__(256) void diff_final_k(
    const float* __restrict__ partial, int np, float* __restrict__ th_out, float inv_n)
{
    float s = 0.f;
    for (int i = threadIdx.x; i < np; i += 256) s += partial[i];
    __shared__ float sm[256];
    sm[threadIdx.x] = s;
    __syncthreads();
    for (int o = 128; o > 0; o >>= 1) {
        if (threadIdx.x < o) sm[threadIdx.x] += sm[threadIdx.x + o];
        __syncthreads();
    }
    if (threadIdx.x == 0) {
        float d = sm[0] * inv_n;
        th_out[0] = 1.f / (1.f + expf(-d));
    }
}

__global__ __launch_bounds__(256) void mix_apply_k(
    float* __restrict__ h, const float* __restrict__ r,
    const float* __restrict__ th_p, long n4)
{
    const float th = th_p[0];
    const float om = 1.f - th;
    long gid = (long)blockIdx.x * 256 + threadIdx.x;
    long stride = (long)gridDim.x * 256;
    for (long i = gid; i < n4; i += stride) {
        float4 a = reinterpret_cast<float4*>(h)[i];
        float4 b = reinterpret_cast<const float4*>(r)[i];
        a.x = th * a.x + om * b.x;
        a.y = th * a.y + om * b.y;
        a.z = th * a.z + om * b.z;
        a.w = th * a.w + om * b.w;
        reinterpret_cast<float4*>(h)[i] = a;
    }
}

// ---------------------------------------------------------------------------
// wavelet coeff + per-feature scale/bias (agg writes bf16 for the next GEMM)
// ---------------------------------------------------------------------------
__global__ void coeff_k(const float* __restrict__ logits, const float* __restrict__ gumb,
                        const float* __restrict__ Wnl, float* __restrict__ coeff)
{
    int f = threadIdx.x;
    float l0 = logits[0] + gumb[f * 3 + 0];
    float l1 = logits[1] + gumb[f * 3 + 1];
    float l2 = logits[2] + gumb[f * 3 + 2];
    int bl = 0;
    float bv = l0;
    if (l1 > bv) { bv = l1; bl = 1; }
    if (l2 > bv) { bv = l2; bl = 2; }
    float s = 0.f;
    #pragma unroll
    for (int t = 0; t < 8; ++t) s += Wnl[f * 8 + t] * PAT[bl][t];
    coeff[f] = s;
}

__global__ __launch_bounds__(256) void aggb_k(
    const float* __restrict__ h, const float* __restrict__ coeff,
    const float* __restrict__ bnl, __hip_bfloat16* __restrict__ out, long n4, int F4)
{
    long gid = (long)blockIdx.x * 256 + threadIdx.x;
    long stride = (long)gridDim.x * 256;
    for (long i = gid; i < n4; i += stride) {
        int f4 = (int)(i % F4);
        float4 c = reinterpret_cast<const float4*>(coeff)[f4];
        float4 b = reinterpret_cast<const float4*>(bnl)[f4];
        float4 v = reinterpret_cast<const float4*>(h)[i];
        ushort4 u;
        u.x = f2bfu(v.x * c.x + b.x);
        u.y = f2bfu(v.y * c.y + b.y);
        u.z = f2bfu(v.z * c.z + b.z);
        u.w = f2bfu(v.w * c.w + b.w);
        reinterpret_cast<ushort4*>(out)[i] = u;
    }
}

// ---------------------------------------------------------------------------
extern "C" void kernel_launch(void* const* d_in, const int* in_sizes, int n_in,
                              void* d_out, int out_size, void* d_ws, size_t ws_size,
                              hipStream_t stream)
{
    const float* x       = (const float*)d_in[0];
    const float* adj     = (const float*)d_in[1];
    const float* Wres    = (const float*)d_in[2];
    const float* bres    = (const float*)d_in[3];
    const float* Wg0     = (const float*)d_in[4];
    const float* bg0     = (const float*)d_in[5];
    const float* Wrg0    = (const float*)d_in[6];
    const float* brg0    = (const float*)d_in[7];
    const float* logits0 = (const float*)d_in[8];
    const float* gumb0   = (const float*)d_in[9];
    const float* Wnl0    = (const float*)d_in[10];
    const float* bnl0    = (const float*)d_in[11];
    const float* Wwo0    = (const float*)d_in[12];
    const float* bwo0    = (const float*)d_in[13];
    const float* Wrw0    = (const float*)d_in[14];
    const float* brw0    = (const float*)d_in[15];
    const float* Wg1     = (const float*)d_in[16];
    const float* bg1     = (const float*)d_in[17];
    const float* Wrg1    = (const float*)d_in[18];
    const float* brg1    = (const float*)d_in[19];
    const float* logits1 = (const float*)d_in[20];
    const float* gumb1   = (const float*)d_in[21];
    const float* Wnl1    = (const float*)d_in[22];
    const float* bnl1    = (const float*)d_in[23];
    const float* Wwo1    = (const float*)d_in[24];
    const float* bwo1    = (const float*)d_in[25];
    const float* Wrw1    = (const float*)d_in[26];
    const float* brw1    = (const float*)d_in[27];

    float* out = (float*)d_out;

    // ---- workspace layout ----
    char* w = (char*)d_ws;
    auto alloc = [&](long bytes) { char* p = w; w += (bytes + 255) & ~255L; return p; };
    float* BufA = (float*)alloc((long)BNR * HH * 4);                 // 64 MB
    float* BufB = (float*)alloc((long)BNR * HH * 4);                 // 64 MB
    __hip_bfloat16* Rg1  = (__hip_bfloat16*)alloc((long)BNR * HH * 2); // 32 MB
    __hip_bfloat16* Rg2  = (__hip_bfloat16*)alloc((long)BNR * HH * 2); // 32 MB
    __hip_bfloat16* Rbf  = (__hip_bfloat16*)alloc((long)BNR * DOUT * 2); // 8 MB
    __hip_bfloat16* adjb = (__hip_bfloat16*)alloc((long)NN * NN * 2);  // 0.5 MB
    __hip_bfloat16* WT   = (__hip_bfloat16*)alloc(221184L * 2);
    float* partial = (float*)alloc(2048 * 4);
    float* th_s    = (float*)alloc(16);
    float* c0      = (float*)alloc(256 * 4);
    float* c1      = (float*)alloc(256 * 4);

    // time-multiplexed bf16 buffers
    __hip_bfloat16* xbf  = Rg1;                       // dead after G2
    __hip_bfloat16* xT   = Rg1 + (long)BNR * DIN;     // dead after G2
    __hip_bfloat16* T0   = Rg1 + 2L * (long)BNR * DIN;// dead after G3
    __hip_bfloat16* Agg0 = Rg1;                       // dead after G6
    __hip_bfloat16* xwT  = Rg1;                       // dead after G9
    __hip_bfloat16* T1   = Rg2;                       // dead after G10
    __hip_bfloat16* Agg1 = Rg1;                       // dead after G13

    // transposed weights inside WT
    __hip_bfloat16* WresT = WT;             // 64x64
    __hip_bfloat16* Wg0T  = WT + 4096;      // 256x64
    __hip_bfloat16* Wrg0T = WT + 20480;     // 256x64
    __hip_bfloat16* Wwo0T = WT + 36864;     // 256x256
    __hip_bfloat16* Wrw0T = WT + 102400;    // 256x64
    __hip_bfloat16* Wg1T  = WT + 118784;    // 256x256
    __hip_bfloat16* Wrg1T = WT + 184320;    // 256x64
    __hip_bfloat16* Wwo1T = WT + 200704;    // 64x256
    __hip_bfloat16* Wrw1T = WT + 217088;    // 64x64

    const dim3 blk(256);

    auto g128 = [&](const __hip_bfloat16* A, const __hip_bfloat16* Bt,
                    const float* bias, const float* resid, float* Cf, __hip_bfloat16* Cb,
                    int M, int N, int K, int bat, long sA, long sB, long sC) {
        dim3 grid(N / 128, M / 128, bat);
        hipLaunchKernelGGL((gemm_bt_k<128, 128, 4, 4>), grid, blk, 0, stream,
                           A, Bt, bias, resid, Cf, Cb, M, N, K, sA, sB, sC);
    };
    auto g64 = [&](const __hip_bfloat16* A, const __hip_bfloat16* Bt,
                   const float* bias, const float* resid, float* Cf, __hip_bfloat16* Cb,
                   int M, int N, int K, int bat, long sA, long sB, long sC) {
        dim3 grid(N / 64, M / 128, bat);
        hipLaunchKernelGGL((gemm_bt_k<128, 64, 4, 2>), grid, blk, 0, stream,
                           A, Bt, bias, resid, Cf, Cb, M, N, K, sA, sB, sC);
    };
    auto mix = [&](float* h, const float* r, long n) {
        long n4 = n / 4;
        hipLaunchKernelGGL(diff_partial_k, dim3(2048), blk, 0, stream, h, r, partial, n4);
        hipLaunchKernelGGL(diff_final_k, dim3(1), blk, 0, stream, partial, 2048, th_s, 1.0f / (float)n);
        hipLaunchKernelGGL(mix_apply_k, dim3(2048), blk, 0, stream, h, r, th_s, n4);
    };

    // ---- input conversions ----
    hipLaunchKernelGGL(cvt_k, dim3(2048), blk, 0, stream, x, xbf, (long)BNR * DIN / 4);
    hipLaunchKernelGGL(cvt_k, dim3(256), blk, 0, stream, adj, adjb, (long)NN * NN / 4);
    hipLaunchKernelGGL(tcvt_k, dim3(1, 8, 128), blk, 0, stream, x, xT, NN, DIN, (long)NN * DIN);
    WTArgs wa;
    wa.src[0] = Wres; wa.dst[0] = WresT; wa.R[0] = 64;  wa.C[0] = 64;
    wa.src[1] = Wg0;  wa.dst[1] = Wg0T;  wa.R[1] = 64;  wa.C[1] = 256;
    wa.src[2] = Wrg0; wa.dst[2] = Wrg0T; wa.R[2] = 64;  wa.C[2] = 256;
    wa.src[3] = Wwo0; wa.dst[3] = Wwo0T; wa.R[3] = 256; wa.C[3] = 256;
    wa.src[4] = Wrw0; wa.dst[4] = Wrw0T; wa.R[4] = 64;  wa.C[4] = 256;
    wa.src[5] = Wg1;  wa.dst[5] = Wg1T;  wa.R[5] = 256; wa.C[5] = 256;
    wa.src[6] = Wrg1; wa.dst[6] = Wrg1T; wa.R[6] = 64;  wa.C[6] = 256;
    wa.src[7] = Wwo1; wa.dst[7] = Wwo1T; wa.R[7] = 256; wa.C[7] = 64;
    wa.src[8] = Wrw1; wa.dst[8] = Wrw1T; wa.R[8] = 64;  wa.C[8] = 64;
    hipLaunchKernelGGL(tcvt_w_k, dim3(16, 9), blk, 0, stream, wa);

    // ---- res = x @ Wres + bres (bf16 out, only used as GEMM A-operand) ----
    g64(xbf, WresT, bres, nullptr, nullptr, Rbf, BNR, 64, 64, 1, 0, 0, 0);

    // ---- layer 0 ----
    // T0 = adj @ x (batched, bf16 out)
    g64(adjb, xT, nullptr, nullptr, nullptr, T0, NN, DIN, NN, BB,
        0, (long)DIN * NN, (long)NN * DIN);
    // xg = T0 @ Wg0 + bg0
    g128(T0, Wg0T, bg0, nullptr, BufA, nullptr, BNR, HH, DIN, 1, 0, 0, 0);
    // rg0 = res @ Wrg0 + brg0
    g128(Rbf, Wrg0T, brg0, nullptr, BufB, nullptr, BNR, HH, DOUT, 1, 0, 0, 0);
    mix(BufA, BufB, (long)BNR * HH);
    // wavelet 0
    hipLaunchKernelGGL(coeff_k, dim3(1), dim3(256), 0, stream, logits0, gumb0, Wnl0, c0);
    hipLaunchKernelGGL(aggb_k, dim3(2048), blk, 0, stream, BufA, c0, bnl0, Agg0,
                       (long)BNR * HH / 4, HH / 4);
    // xw = Agg0 @ Wwo0 + bwo0 + xg
    g128(Agg0, Wwo0T, bwo0, BufA, BufB, nullptr, BNR, HH, HH, 1, 0, 0, 0);
    // rw0 = res @ Wrw0 + brw0
    g128(Rbf, Wrw0T, brw0, nullptr, BufA, nullptr, BNR, HH, DOUT, 1, 0, 0, 0);
    mix(BufB, BufA, (long)BNR * HH);   // xw in BufB

    // ---- layer 1 ----
    // xwT (batched transpose-convert of xw)
    hipLaunchKernelGGL(tcvt_k, dim3(4, 8, 128), blk, 0, stream, BufB, xwT, NN, HH, (long)NN * HH);
    // T1 = adj @ xw (batched, bf16 out)
    g128(adjb, xwT, nullptr, nullptr, nullptr, T1, NN, HH, NN, BB,
         0, (long)HH * NN, (long)NN * HH);
    // xg1 = T1 @ Wg1 + bg1 + xw
    g128(T1, Wg1T, bg1, BufB, BufA, nullptr, BNR, HH, HH, 1, 0, 0, 0);
    // rg1 = res @ Wrg1 + brg1
    g128(Rbf, Wrg1T, brg1, nullptr, BufB, nullptr, BNR, HH, DOUT, 1, 0, 0, 0);
    mix(BufA, BufB, (long)BNR * HH);
    // wavelet 1 (256 -> 64)
    hipLaunchKernelGGL(coeff_k, dim3(1), dim3(256), 0, stream, logits1, gumb1, Wnl1, c1);
    hipLaunchKernelGGL(aggb_k, dim3(2048), blk, 0, stream, BufA, c1, bnl1, Agg1,
                       (long)BNR * HH / 4, HH / 4);
    g64(Agg1, Wwo1T, bwo1, nullptr, out, nullptr, BNR, DOUT, HH, 1, 0, 0, 0);
    // rw1 = res @ Wrw1 + brw1
    g64(Rbf, Wrw1T, brw1, nullptr, BufA, nullptr, BNR, DOUT, DIN, 1, 0, 0, 0);
    mix(out, BufA, (long)BNR * DOUT);
}

// Round 3
// 364.500 us; speedup vs baseline: 2.8558x; 1.4407x over previous
//
#include <hip/hip_runtime.h>
#include <hip/hip_bf16.h>
#include <math.h>

#define BB   128
#define NN   512
#define DIN  64
#define HH   256
#define DOUT 64
#define BNR  (BB * NN)          // 65536 rows

typedef float  f32x4  __attribute__((ext_vector_type(4)));
typedef __bf16 bf16x8 __attribute__((ext_vector_type(8)));

#define GLP(p)  ((const __attribute__((address_space(1))) void*)(p))
#define LDSP(p) ((__attribute__((address_space(3))) void*)(p))

// Haar/db1 'zero' DWT patterns, levels 1..3, FULL_LEN=8
__constant__ float PAT[3][8] = {
    {0.70710678f, 0.70710678f, 0.f, 0.f, 0.f, 0.f, 0.f, 0.f},
    {0.5f,        0.70710678f, 0.f, 0.5f, 0.f, 0.f, 0.f, 0.f},
    {0.35355339f, 0.70710678f, 0.f, 0.f, 0.f, 0.5f, 0.f, 0.35355339f}
};

__device__ __forceinline__ unsigned short f2bfu(float x) {
    __hip_bfloat16 b = __float2bfloat16(x);
    unsigned short u;
    __builtin_memcpy(&u, &b, 2);
    return u;
}
__device__ __forceinline__ float bf2f(unsigned short u) {
    unsigned int v = ((unsigned int)u) << 16;
    float f;
    __builtin_memcpy(&f, &v, 4);
    return f;
}

// ---------------------------------------------------------------------------
// fp32 -> bf16 convert
// ---------------------------------------------------------------------------
__global__ __launch_bounds__(256) void cvt_k(const float* __restrict__ in,
                                             unsigned short* __restrict__ out, long n4)
{
    long gid = (long)blockIdx.x * 256 + threadIdx.x;
    long stride = (long)gridDim.x * 256;
    for (long i = gid; i < n4; i += stride) {
        float4 v = reinterpret_cast<const float4*>(in)[i];
        ushort4 u;
        u.x = f2bfu(v.x); u.y = f2bfu(v.y); u.z = f2bfu(v.z); u.w = f2bfu(v.w);
        reinterpret_cast<ushort4*>(out)[i] = u;
    }
}

// ---------------------------------------------------------------------------
// transpose-convert fp32 (bz,R,C) -> bf16 (bz,C,R); 64x64 tiles
// ---------------------------------------------------------------------------
__device__ __forceinline__ void tcvt_body(const float* __restrict__ in,
                                          unsigned short* __restrict__ out,
                                          int R, int C, int r0, int c0)
{
    __shared__ float t[64][65];
    int tr = threadIdx.x >> 6;
    int tc = threadIdx.x & 63;
    #pragma unroll
    for (int i = 0; i < 16; ++i) {
        int r = i * 4 + tr;
        t[r][tc] = in[(long)(r0 + r) * C + c0 + tc];
    }
    __syncthreads();
    #pragma unroll
    for (int i = 0; i < 16; ++i) {
        int r = i * 4 + tr;
        out[(long)(c0 + r) * R + r0 + tc] = f2bfu(t[tc][r]);
    }
}

__global__ __launch_bounds__(256) void tcvt_k(const float* __restrict__ in,
                                              unsigned short* __restrict__ out,
                                              int R, int C, long sz)
{
    long base = (long)blockIdx.z * sz;
    tcvt_body(in + base, out + base, R, C, blockIdx.y * 64, blockIdx.x * 64);
}

struct WTArgs {
    const float* src[9];
    unsigned short* dst[9];
    int R[9], C[9];
};
__global__ __launch_bounds__(256) void tcvt_w_k(WTArgs a)
{
    int wgt = blockIdx.y;
    int R = a.R[wgt], C = a.C[wgt];
    int tilesX = C >> 6;
    int tiles = (R >> 6) * tilesX;
    int t = blockIdx.x;
    if (t >= tiles) return;
    tcvt_body(a.src[wgt], a.dst[wgt], R, C, (t / tilesX) * 64, (t % tilesX) * 64);
}

// ---------------------------------------------------------------------------
// Single MFMA bf16 GEMM (bf16 out): C[bz](M,N) = A[bz](M,K)@B, Bt(N,K) row-major
// Same verified structure as round 2 (swizzled global_load_lds staging).
// ---------------------------------------------------------------------------
template<int BM, int BN, int FM, int FN>
__global__ __launch_bounds__(256) void gemm_bt_k(
    const __hip_bfloat16* __restrict__ A, const __hip_bfloat16* __restrict__ Bt,
    const float* __restrict__ bias, __hip_bfloat16* __restrict__ Cb,
    int M, int N, int K, long sA, long sB, long sC)
{
    __shared__ __attribute__((aligned(128))) char lds[(BM + BN) * 128];
    char* AsB = lds;
    char* BsB = lds + BM * 128;

    const long bz = blockIdx.z;
    const __hip_bfloat16* Ab = A + bz * sA;
    const __hip_bfloat16* Bb = Bt + bz * sB;

    const int m0 = blockIdx.y * BM;
    const int n0 = blockIdx.x * BN;
    const int tid  = threadIdx.x;
    const int wave = tid >> 6;
    const int lane = tid & 63;
    const int wm = wave >> 1, wn = wave & 1;

    const int NCH = (BM + BN) / 32;
    const int lr = lane >> 3;
    const int ls = lane & 7;

    f32x4 acc[FM][FN];
    #pragma unroll
    for (int i = 0; i < FM; ++i)
        #pragma unroll
        for (int j = 0; j < FN; ++j)
            acc[i][j] = (f32x4){0.f, 0.f, 0.f, 0.f};

    for (int k0 = 0; k0 < K; k0 += 64) {
        #pragma unroll
        for (int cc = 0; cc < NCH; ++cc) {
            int c = wave * NCH + cc;
            const __hip_bfloat16* src;
            char* ldsb;
            if (c < BM / 8) {
                int r = c * 8 + lr;
                ldsb = AsB + c * 1024;
                src = Ab + ((long)(m0 + r) * K + k0 + ((ls ^ (r & 7)) << 3));
            } else {
                int c2 = c - BM / 8;
                int r = c2 * 8 + lr;
                ldsb = BsB + c2 * 1024;
                src = Bb + ((long)(n0 + r) * K + k0 + ((ls ^ (r & 7)) << 3));
            }
            __builtin_amdgcn_global_load_lds(GLP(src), LDSP(ldsb), 16, 0, 0);
        }
        __syncthreads();

        #pragma unroll
        for (int ksl = 0; ksl < 2; ++ksl) {
            bf16x8 af[FM], bfr[FN];
            #pragma unroll
            for (int i = 0; i < FM; ++i) {
                int row = wm * (FM * 16) + i * 16 + (lane & 15);
                int off = (ksl * 64 + ((lane >> 4) << 4)) ^ ((row & 7) << 4);
                af[i] = *reinterpret_cast<const bf16x8*>(AsB + row * 128 + off);
            }
            #pragma unroll
            for (int j = 0; j < FN; ++j) {
                int row = wn * (FN * 16) + j * 16 + (lane & 15);
                int off = (ksl * 64 + ((lane >> 4) << 4)) ^ ((row & 7) << 4);
                bfr[j] = *reinterpret_cast<const bf16x8*>(BsB + row * 128 + off);
            }
            #pragma unroll
            for (int i = 0; i < FM; ++i)
                #pragma unroll
                for (int j = 0; j < FN; ++j)
                    acc[i][j] = __builtin_amdgcn_mfma_f32_16x16x32_bf16(
                        af[i], bfr[j], acc[i][j], 0, 0, 0);
        }
        __syncthreads();
    }

    const int lc  = lane & 15;
    const int lr4 = (lane >> 4) << 2;
    #pragma unroll
    for (int j = 0; j < FN; ++j) {
        int col = n0 + wn * (FN * 16) + j * 16 + lc;
        float bv = bias ? bias[col] : 0.0f;
        #pragma unroll
        for (int i = 0; i < FM; ++i) {
            int row0 = m0 + wm * (FM * 16) + i * 16 + lr4;
            #pragma unroll
            for (int r = 0; r < 4; ++r) {
                long idx = bz * sC + (long)(row0 + r) * N + col;
                Cb[idx] = __float2bfloat16(acc[i][j][r] + bv);
            }
        }
    }
}

// ---------------------------------------------------------------------------
// Dual MFMA GEMM + in-register diff reduction:
//   C1 = A1@B1 + bias1 (+resid1 bf16), C2 = A2@B2 + bias2,
//   partial[block] = sum over block's tile of (C1-C2)^2 (fp32, pre-rounding).
// Single batch; M rows. C1,C2 written bf16.
// ---------------------------------------------------------------------------
template<int BM, int BN, int FM, int FN>
__global__ __launch_bounds__(256) void dual_k(
    const __hip_bfloat16* __restrict__ A1, const __hip_bfloat16* __restrict__ B1t,
    const float* __restrict__ bias1, const __hip_bfloat16* __restrict__ resid1,
    const __hip_bfloat16* __restrict__ A2, const __hip_bfloat16* __restrict__ B2t,
    const float* __restrict__ bias2,
    __hip_bfloat16* __restrict__ C1, __hip_bfloat16* __restrict__ C2,
    float* __restrict__ partial,
    int M, int N, int K1, int K2)
{
    __shared__ __attribute__((aligned(128))) char lds[(BM + BN) * 128];
    char* AsB = lds;
    char* BsB = lds + BM * 128;

    const int m0 = blockIdx.y * BM;
    const int n0 = blockIdx.x * BN;
    const int tid  = threadIdx.x;
    const int wave = tid >> 6;
    const int lane = tid & 63;
    const int wm = wave >> 1, wn = wave & 1;

    const int NCH = (BM + BN) / 32;
    const int lr = lane >> 3;
    const int ls = lane & 7;

    f32x4 acc[2][FM][FN];
    #pragma unroll
    for (int p = 0; p < 2; ++p)
        #pragma unroll
        for (int i = 0; i < FM; ++i)
            #pragma unroll
            for (int j = 0; j < FN; ++j)
                acc[p][i][j] = (f32x4){0.f, 0.f, 0.f, 0.f};

    #pragma unroll
    for (int ph = 0; ph < 2; ++ph) {
        const __hip_bfloat16* Ab = ph ? A2 : A1;
        const __hip_bfloat16* Bb = ph ? B2t : B1t;
        const int K = ph ? K2 : K1;

        for (int k0 = 0; k0 < K; k0 += 64) {
            #pragma unroll
            for (int cc = 0; cc < NCH; ++cc) {
                int c = wave * NCH + cc;
                const __hip_bfloat16* src;
                char* ldsb;
                if (c < BM / 8) {
                    int r = c * 8 + lr;
                    ldsb = AsB + c * 1024;
                    src = Ab + ((long)(m0 + r) * K + k0 + ((ls ^ (r & 7)) << 3));
                } else {
                    int c2 = c - BM / 8;
                    int r = c2 * 8 + lr;
                    ldsb = BsB + c2 * 1024;
                    src = Bb + ((long)(n0 + r) * K + k0 + ((ls ^ (r & 7)) << 3));
                }
                __builtin_amdgcn_global_load_lds(GLP(src), LDSP(ldsb), 16, 0, 0);
            }
            __syncthreads();

            #pragma unroll
            for (int ksl = 0; ksl < 2; ++ksl) {
                bf16x8 af[FM], bfr[FN];
                #pragma unroll
                for (int i = 0; i < FM; ++i) {
                    int row = wm * (FM * 16) + i * 16 + (lane & 15);
                    int off = (ksl * 64 + ((lane >> 4) << 4)) ^ ((row & 7) << 4);
                    af[i] = *reinterpret_cast<const bf16x8*>(AsB + row * 128 + off);
                }
                #pragma unroll
                for (int j = 0; j < FN; ++j) {
                    int row = wn * (FN * 16) + j * 16 + (lane & 15);
                    int off = (ksl * 64 + ((lane >> 4) << 4)) ^ ((row & 7) << 4);
                    bfr[j] = *reinterpret_cast<const bf16x8*>(BsB + row * 128 + off);
                }
                #pragma unroll
                for (int i = 0; i < FM; ++i)
                    #pragma unroll
                    for (int j = 0; j < FN; ++j)
                        acc[ph][i][j] = __builtin_amdgcn_mfma_f32_16x16x32_bf16(
                            af[i], bfr[j], acc[ph][i][j], 0, 0, 0);
            }
            __syncthreads();
        }
    }

    const int lc  = lane & 15;
    const int lr4 = (lane >> 4) << 2;
    float dsum = 0.f;
    #pragma unroll
    for (int j = 0; j < FN; ++j) {
        int col = n0 + wn * (FN * 16) + j * 16 + lc;
        float b1 = bias1 ? bias1[col] : 0.0f;
        float b2 = bias2 ? bias2[col] : 0.0f;
        #pragma unroll
        for (int i = 0; i < FM; ++i) {
            int row0 = m0 + wm * (FM * 16) + i * 16 + lr4;
            #pragma unroll
            for (int r = 0; r < 4; ++r) {
                long idx = (long)(row0 + r) * N + col;
                float v1 = acc[0][i][j][r] + b1;
                if (resid1) v1 += __bfloat162float(resid1[idx]);
                float v2 = acc[1][i][j][r] + b2;
                C1[idx] = __float2bfloat16(v1);
                C2[idx] = __float2bfloat16(v2);
                float d = v1 - v2;
                dsum += d * d;
            }
        }
    }

    __syncthreads();
    float* red = (float*)lds;
    red[tid] = dsum;
    __syncthreads();
    for (int o = 128; o > 0; o >>= 1) {
        if (tid < o) red[tid] += red[tid + o];
        __syncthreads();
    }
    if (tid == 0) partial[blockIdx.y * gridDim.x + blockIdx.x] = red[0];
}

// ---------------------------------------------------------------------------
// th = sigmoid(sum(partial)/n)
// ---------------------------------------------------------------------------
__global__ __launch_bounds__(256) void diff_final_k(
    const float* __restrict__ partial, int np, float* __restrict__ th_out, float inv_n)
{
    float s = 0.f;
    for (int i = threadIdx.x; i < np; i += 256) s += partial[i];
    __shared__ float sm[256];
    sm[threadIdx.x] = s;
    __syncthreads();
    for (int o = 128; o > 0; o >>= 1) {
        if (threadIdx.x < o) sm[threadIdx.x] += sm[threadIdx.x + o];
        __syncthreads();
    }
    if (threadIdx.x == 0) {
        float d = sm[0] * inv_n;
        th_out[0] = 1.f / (1.f + expf(-d));
    }
}

// ---------------------------------------------------------------------------
// wavelet coeff
// ---------------------------------------------------------------------------
__global__ void coeff_k(const float* __restrict__ logits, const float* __restrict__ gumb,
                        const float* __restrict__ Wnl, float* __restrict__ coeff)
{
    int f = threadIdx.x;
    float l0 = logits[0] + gumb[f * 3 + 0];
    float l1 = logits[1] + gumb[f * 3 + 1];
    float l2 = logits[2] + gumb[f * 3 + 2];
    int bl = 0;
    float bv = l0;
    if (l1 > bv) { bv = l1; bl = 1; }
    if (l2 > bv) { bv = l2; bl = 2; }
    float s = 0.f;
    #pragma unroll
    for (int t = 0; t < 8; ++t) s += Wnl[f * 8 + t] * PAT[bl][t];
    coeff[f] = s;
}

// ---------------------------------------------------------------------------
// fused mix + wavelet scale/bias:
//   m = th*h + (1-th)*r ; agg = m*coeff[f] + bnl[f]
// writes agg (bf16) and optionally m (bf16). 8 elems/thread.
// ---------------------------------------------------------------------------
__global__ __launch_bounds__(256) void mixagg_k(
    const unsigned short* __restrict__ h, const unsigned short* __restrict__ r,
    const float* __restrict__ th_p, const float* __restrict__ coeff,
    const float* __restrict__ bnl,
    unsigned short* __restrict__ agg, unsigned short* __restrict__ mout,
    long n8, int F8)
{
    const float th = th_p[0];
    const float om = 1.f - th;
    long gid = (long)blockIdx.x * 256 + threadIdx.x;
    long stride = (long)gridDim.x * 256;
    for (long i = gid; i < n8; i += stride) {
        uint4 hv = reinterpret_cast<const uint4*>(h)[i];
        uint4 rv = reinterpret_cast<const uint4*>(r)[i];
        int f0 = (int)(i % F8) * 8;
        float4 ca = *reinterpret_cast<const float4*>(coeff + f0);
        float4 cb = *reinterpret_cast<const float4*>(coeff + f0 + 4);
        float4 ba = *reinterpret_cast<const float4*>(bnl + f0);
        float4 bb = *reinterpret_cast<const float4*>(bnl + f0 + 4);
        float c[8] = {ca.x, ca.y, ca.z, ca.w, cb.x, cb.y, cb.z, cb.w};
        float b[8] = {ba.x, ba.y, ba.z, ba.w, bb.x, bb.y, bb.z, bb.w};
        unsigned int hw[4] = {hv.x, hv.y, hv.z, hv.w};
        unsigned int rw[4] = {rv.x, rv.y, rv.z, rv.w};
        unsigned int ao[4], mo[4];
        #pragma unroll
        for (int q = 0; q < 4; ++q) {
            float h0 = bf2f((unsigned short)(hw[q] & 0xffff));
            float h1 = bf2f((unsigned short)(hw[q] >> 16));
            float r0 = bf2f((unsigned short)(rw[q] & 0xffff));
            float r1 = bf2f((unsigned short)(rw[q] >> 16));
            float m0 = th * h0 + om * r0;
            float m1 = th * h1 + om * r1;
            float a0 = m0 * c[q * 2] + b[q * 2];
            float a1 = m1 * c[q * 2 + 1] + b[q * 2 + 1];
            ao[q] = (unsigned int)f2bfu(a0) | ((unsigned int)f2bfu(a1) << 16);
            mo[q] = (unsigned int)f2bfu(m0) | ((unsigned int)f2bfu(m1) << 16);
        }
        reinterpret_cast<uint4*>(agg)[i] = make_uint4(ao[0], ao[1], ao[2], ao[3]);
        if (mout)
            reinterpret_cast<uint4*>(mout)[i] = make_uint4(mo[0], mo[1], mo[2], mo[3]);
    }
}

// ---------------------------------------------------------------------------
// fused mix + batched transpose: m = th*h+(1-th)*r;
// writes xw (b,N,H) row-major bf16 and xwT (b,H,N) bf16.
// ---------------------------------------------------------------------------
__global__ __launch_bounds__(256) void mixT_k(
    const unsigned short* __restrict__ h, const unsigned short* __restrict__ r,
    const float* __restrict__ th_p,
    unsigned short* __restrict__ xw, unsigned short* __restrict__ xwT)
{
    const float th = th_p[0];
    const float om = 1.f - th;
    __shared__ float t[64][65];
    const long base = (long)blockIdx.z * NN * HH;
    const int r0 = blockIdx.y * 64;
    const int c0 = blockIdx.x * 64;
    const int tr = threadIdx.x >> 6;
    const int tc = threadIdx.x & 63;
    #pragma unroll
    for (int i = 0; i < 16; ++i) {
        int rr = i * 4 + tr;
        long idx = base + (long)(r0 + rr) * HH + c0 + tc;
        float m = th * bf2f(h[idx]) + om * bf2f(r[idx]);
        xw[idx] = f2bfu(m);
        t[rr][tc] = m;
    }
    __syncthreads();
    #pragma unroll
    for (int i = 0; i < 16; ++i) {
        int rr = i * 4 + tr;
        xwT[base + (long)(c0 + rr) * NN + r0 + tc] = f2bfu(t[tc][rr]);
    }
}

// ---------------------------------------------------------------------------
// final mix: out = th*h + (1-th)*r, fp32 out
// ---------------------------------------------------------------------------
__global__ __launch_bounds__(256) void mixfinal_k(
    const unsigned short* __restrict__ h, const unsigned short* __restrict__ r,
    const float* __restrict__ th_p, float* __restrict__ out, long n4)
{
    const float th = th_p[0];
    const float om = 1.f - th;
    long gid = (long)blockIdx.x * 256 + threadIdx.x;
    long stride = (long)gridDim.x * 256;
    for (long i = gid; i < n4; i += stride) {
        ushort4 hv = reinterpret_cast<const ushort4*>(h)[i];
        ushort4 rv = reinterpret_cast<const ushort4*>(r)[i];
        float4 o;
        o.x = th * bf2f(hv.x) + om * bf2f(rv.x);
        o.y = th * bf2f(hv.y) + om * bf2f(rv.y);
        o.z = th * bf2f(hv.z) + om * bf2f(rv.z);
        o.w = th * bf2f(hv.w) + om * bf2f(rv.w);
        reinterpret_cast<float4*>(out)[i] = o;
    }
}

// ---------------------------------------------------------------------------
extern "C" void kernel_launch(void* const* d_in, const int* in_sizes, int n_in,
                              void* d_out, int out_size, void* d_ws, size_t ws_size,
                              hipStream_t stream)
{
    const float* x       = (const float*)d_in[0];
    const float* adj     = (const float*)d_in[1];
    const float* Wres    = (const float*)d_in[2];
    const float* bres    = (const float*)d_in[3];
    const float* Wg0     = (const float*)d_in[4];
    const float* bg0     = (const float*)d_in[5];
    const float* Wrg0    = (const float*)d_in[6];
    const float* brg0    = (const float*)d_in[7];
    const float* logits0 = (const float*)d_in[8];
    const float* gumb0   = (const float*)d_in[9];
    const float* Wnl0    = (const float*)d_in[10];
    const float* bnl0    = (const float*)d_in[11];
    const float* Wwo0    = (const float*)d_in[12];
    const float* bwo0    = (const float*)d_in[13];
    const float* Wrw0    = (const float*)d_in[14];
    const float* brw0    = (const float*)d_in[15];
    const float* Wg1     = (const float*)d_in[16];
    const float* bg1     = (const float*)d_in[17];
    const float* Wrg1    = (const float*)d_in[18];
    const float* brg1    = (const float*)d_in[19];
    const float* logits1 = (const float*)d_in[20];
    const float* gumb1   = (const float*)d_in[21];
    const float* Wnl1    = (const float*)d_in[22];
    const float* bnl1    = (const float*)d_in[23];
    const float* Wwo1    = (const float*)d_in[24];
    const float* bwo1    = (const float*)d_in[25];
    const float* Wrw1    = (const float*)d_in[26];
    const float* brw1    = (const float*)d_in[27];

    float* out = (float*)d_out;

    // ---- workspace ----
    char* w = (char*)d_ws;
    auto alloc = [&](long bytes) { char* p = w; w += (bytes + 255) & ~255L; return p; };
    const long SLOT = (long)BNR * HH * 2;                 // 32 MB
    char* pool = alloc(6 * SLOT);                         // 192 MB
    __hip_bfloat16* Rbf  = (__hip_bfloat16*)alloc((long)BNR * DOUT * 2); // 8 MB
    __hip_bfloat16* adjb = (__hip_bfloat16*)alloc((long)NN * NN * 2);
    __hip_bfloat16* WT   = (__hip_bfloat16*)alloc(221184L * 2);
    float* partial = (float*)alloc(1024 * 4);
    float* th_s    = (float*)alloc(16);
    float* c0      = (float*)alloc(256 * 4);
    float* c1      = (float*)alloc(256 * 4);

    auto S = [&](int i) { return pool + (long)i * SLOT; };
    // slot timeline (all bf16):
    __hip_bfloat16* xbf  = (__hip_bfloat16*)S(1);
    __hip_bfloat16* xT   = (__hip_bfloat16*)(S(1) + (long)BNR * DIN * 2);
    __hip_bfloat16* T0   = (__hip_bfloat16*)S(0);
    __hip_bfloat16* xg   = (__hip_bfloat16*)S(2);
    __hip_bfloat16* rg   = (__hip_bfloat16*)S(3);
    __hip_bfloat16* Agg0 = (__hip_bfloat16*)S(0);
    __hip_bfloat16* m0   = (__hip_bfloat16*)S(1);
    __hip_bfloat16* xwr  = (__hip_bfloat16*)S(2);   // xw_raw
    __hip_bfloat16* rw0  = (__hip_bfloat16*)S(3);
    __hip_bfloat16* xw   = (__hip_bfloat16*)S(0);
    __hip_bfloat16* xwT  = (__hip_bfloat16*)S(1);
    __hip_bfloat16* T1   = (__hip_bfloat16*)S(2);
    __hip_bfloat16* xg1  = (__hip_bfloat16*)S(1);
    __hip_bfloat16* rg1  = (__hip_bfloat16*)S(3);
    __hip_bfloat16* Agg1 = (__hip_bfloat16*)S(2);
    __hip_bfloat16* orw  = (__hip_bfloat16*)S(1);   // o_raw
    __hip_bfloat16* rw1  = (__hip_bfloat16*)S(3);

    // transposed weights
    __hip_bfloat16* WresT = WT;             // 64x64
    __hip_bfloat16* Wg0T  = WT + 4096;      // 256x64
    __hip_bfloat16* Wrg0T = WT + 20480;     // 256x64
    __hip_bfloat16* Wwo0T = WT + 36864;     // 256x256
    __hip_bfloat16* Wrw0T = WT + 102400;    // 256x64
    __hip_bfloat16* Wg1T  = WT + 118784;    // 256x256
    __hip_bfloat16* Wrg1T = WT + 184320;    // 256x64
    __hip_bfloat16* Wwo1T = WT + 200704;    // 64x256
    __hip_bfloat16* Wrw1T = WT + 217088;    // 64x64

    const dim3 blk(256);
    const float invH = 1.0f / ((float)BNR * HH);
    const float invD = 1.0f / ((float)BNR * DOUT);

    // ---- conversions ----
    hipLaunchKernelGGL(cvt_k, dim3(2048), blk, 0, stream, x, (unsigned short*)xbf, (long)BNR * DIN / 4);
    hipLaunchKernelGGL(cvt_k, dim3(256), blk, 0, stream, adj, (unsigned short*)adjb, (long)NN * NN / 4);
    hipLaunchKernelGGL(tcvt_k, dim3(1, 8, 128), blk, 0, stream, x, (unsigned short*)xT, NN, DIN, (long)NN * DIN);
    WTArgs wa;
    wa.src[0] = Wres; wa.dst[0] = (unsigned short*)WresT; wa.R[0] = 64;  wa.C[0] = 64;
    wa.src[1] = Wg0;  wa.dst[1] = (unsigned short*)Wg0T;  wa.R[1] = 64;  wa.C[1] = 256;
    wa.src[2] = Wrg0; wa.dst[2] = (unsigned short*)Wrg0T; wa.R[2] = 64;  wa.C[2] = 256;
    wa.src[3] = Wwo0; wa.dst[3] = (unsigned short*)Wwo0T; wa.R[3] = 256; wa.C[3] = 256;
    wa.src[4] = Wrw0; wa.dst[4] = (unsigned short*)Wrw0T; wa.R[4] = 64;  wa.C[4] = 256;
    wa.src[5] = Wg1;  wa.dst[5] = (unsigned short*)Wg1T;  wa.R[5] = 256; wa.C[5] = 256;
    wa.src[6] = Wrg1; wa.dst[6] = (unsigned short*)Wrg1T; wa.R[6] = 64;  wa.C[6] = 256;
    wa.src[7] = Wwo1; wa.dst[7] = (unsigned short*)Wwo1T; wa.R[7] = 256; wa.C[7] = 64;
    wa.src[8] = Wrw1; wa.dst[8] = (unsigned short*)Wrw1T; wa.R[8] = 64;  wa.C[8] = 64;
    hipLaunchKernelGGL(tcvt_w_k, dim3(16, 9), blk, 0, stream, wa);

    // coeffs (no deps on activations)
    hipLaunchKernelGGL(coeff_k, dim3(1), dim3(256), 0, stream, logits0, gumb0, Wnl0, c0);
    hipLaunchKernelGGL(coeff_k, dim3(1), dim3(256), 0, stream, logits1, gumb1, Wnl1, c1);

    // res = x @ Wres + bres
    hipLaunchKernelGGL((gemm_bt_k<128, 64, 4, 2>), dim3(1, BNR / 128, 1), blk, 0, stream,
                       xbf, WresT, bres, Rbf, BNR, DOUT, DIN, 0, 0, 0);

    // T0 = adj @ x (batched)
    hipLaunchKernelGGL((gemm_bt_k<128, 64, 4, 2>), dim3(1, 4, BB), blk, 0, stream,
                       adjb, xT, nullptr, T0, NN, DIN, NN, 0, (long)DIN * NN, (long)NN * DIN);

    // dual0: xg = T0@Wg0+bg0 ; rg = Rbf@Wrg0+brg0 (+diff)
    hipLaunchKernelGGL((dual_k<128, 128, 4, 4>), dim3(2, BNR / 128), blk, 0, stream,
                       T0, Wg0T, bg0, (const __hip_bfloat16*)nullptr,
                       Rbf, Wrg0T, brg0, xg, rg, partial, BNR, HH, DIN, DOUT);
    hipLaunchKernelGGL(diff_final_k, dim3(1), blk, 0, stream, partial, 1024, th_s + 0, invH);

    // mix + agg (also writes mixed m0 for the xw residual)
    hipLaunchKernelGGL(mixagg_k, dim3(2048), blk, 0, stream,
                       (const unsigned short*)xg, (const unsigned short*)rg, th_s + 0, c0, bnl0,
                       (unsigned short*)Agg0, (unsigned short*)m0, (long)BNR * HH / 8, HH / 8);

    // dual_w0: xw_raw = Agg0@Wwo0+bwo0+m0 ; rw0 = Rbf@Wrw0+brw0 (+diff)
    hipLaunchKernelGGL((dual_k<128, 128, 4, 4>), dim3(2, BNR / 128), blk, 0, stream,
                       Agg0, Wwo0T, bwo0, m0,
                       Rbf, Wrw0T, brw0, xwr, rw0, partial, BNR, HH, HH, DOUT);
    hipLaunchKernelGGL(diff_final_k, dim3(1), blk, 0, stream, partial, 1024, th_s + 1, invH);

    // mix + transpose -> xw (row-major) + xwT
    hipLaunchKernelGGL(mixT_k, dim3(4, 8, BB), blk, 0, stream,
                       (const unsigned short*)xwr, (const unsigned short*)rw0, th_s + 1,
                       (unsigned short*)xw, (unsigned short*)xwT);

    // T1 = adj @ xw (batched)
    hipLaunchKernelGGL((gemm_bt_k<128, 128, 4, 4>), dim3(2, 4, BB), blk, 0, stream,
                       adjb, xwT, nullptr, T1, NN, HH, NN, 0, (long)HH * NN, (long)NN * HH);

    // dual1: xg1 = T1@Wg1+bg1+xw ; rg1 = Rbf@Wrg1+brg1 (+diff)
    hipLaunchKernelGGL((dual_k<128, 128, 4, 4>), dim3(2, BNR / 128), blk, 0, stream,
                       T1, Wg1T, bg1, xw,
                       Rbf, Wrg1T, brg1, xg1, rg1, partial, BNR, HH, HH, DOUT);
    hipLaunchKernelGGL(diff_final_k, dim3(1), blk, 0, stream, partial, 1024, th_s + 2, invH);

    // mix + agg (no mixed output needed)
    hipLaunchKernelGGL(mixagg_k, dim3(2048), blk, 0, stream,
                       (const unsigned short*)xg1, (const unsigned short*)rg1, th_s + 2, c1, bnl1,
                       (unsigned short*)Agg1, (unsigned short*)nullptr, (long)BNR * HH / 8, HH / 8);

    // dual_out: o_raw = Agg1@Wwo1+bwo1 ; rw1 = Rbf@Wrw1+brw1 (+diff)
    hipLaunchKernelGGL((dual_k<128, 64, 4, 2>), dim3(1, BNR / 128), blk, 0, stream,
                       Agg1, Wwo1T, bwo1, (const __hip_bfloat16*)nullptr,
                       Rbf, Wrw1T, brw1, orw, rw1, partial, BNR, DOUT, HH, DIN);
    hipLaunchKernelGGL(diff_final_k, dim3(1), blk, 0, stream, partial, 512, th_s + 3, invD);

    // final mix -> fp32 out
    hipLaunchKernelGGL(mixfinal_k, dim3(2048), blk, 0, stream,
                       (const unsigned short*)orw, (const unsigned short*)rw1, th_s + 3,
                       out, (long)BNR * DOUT / 4);
}

// Round 4
// 289.960 us; speedup vs baseline: 3.5899x; 1.2571x over previous
//
#include <hip/hip_runtime.h>
#include <hip/hip_bf16.h>
#include <math.h>

#define BB   128
#define NN   512
#define DIN  64
#define HH   256
#define DOUT 64
#define BNR  (BB * NN)          // 65536 rows

typedef float  f32x4  __attribute__((ext_vector_type(4)));
typedef __bf16 bf16x8 __attribute__((ext_vector_type(8)));

#define GLP(p)  ((const __attribute__((address_space(1))) void*)(p))
#define LDSP(p) ((__attribute__((address_space(3))) void*)(p))

// Haar/db1 'zero' DWT patterns, levels 1..3, FULL_LEN=8
__constant__ float PAT[3][8] = {
    {0.70710678f, 0.70710678f, 0.f, 0.f, 0.f, 0.f, 0.f, 0.f},
    {0.5f,        0.70710678f, 0.f, 0.5f, 0.f, 0.f, 0.f, 0.f},
    {0.35355339f, 0.70710678f, 0.f, 0.f, 0.f, 0.5f, 0.f, 0.35355339f}
};

__device__ __forceinline__ unsigned short f2bfu(float x) {
    __hip_bfloat16 b = __float2bfloat16(x);
    unsigned short u;
    __builtin_memcpy(&u, &b, 2);
    return u;
}
__device__ __forceinline__ float bf2f(unsigned short u) {
    unsigned int v = ((unsigned int)u) << 16;
    float f;
    __builtin_memcpy(&f, &v, 4);
    return f;
}

// ---------------------------------------------------------------------------
// Coalesced bf16 tile write via LDS staging.
// Fragments (col=lane&15, row=(lane>>4)*4+r per verified C/D layout) are
// ds_write_b16'd into a [BM][BN] bf16 LDS tile with byte-swizzle
// colb ^= ((row>>2)&3)<<5  (spreads the 4-row fragment stride over 4 bank
// groups -> 2 lanes/bank, free). Then 16B/lane coalesced global stores.
// Caller guarantees lds (>= BM*BN*2 bytes) is dead. Starts+contains syncs.
// ---------------------------------------------------------------------------
template<int BM, int BN, int FM, int FN>
__device__ __forceinline__ void write_tile(char* lds, f32x4 (&a)[FM][FN],
                                           __hip_bfloat16* __restrict__ C,
                                           long base, int N, int tid)
{
    const int wave = tid >> 6;
    const int lane = tid & 63;
    const int wm = wave >> 1, wn = wave & 1;
    const int lc = lane & 15;
    const int lr4 = (lane >> 4) << 2;
    __syncthreads();
    #pragma unroll
    for (int j = 0; j < FN; ++j) {
        int colb = (wn * (FN * 16) + j * 16 + lc) * 2;
        #pragma unroll
        for (int i = 0; i < FM; ++i) {
            int row0 = wm * (FM * 16) + i * 16 + lr4;
            #pragma unroll
            for (int r = 0; r < 4; ++r) {
                int row = row0 + r;
                *reinterpret_cast<unsigned short*>(
                    lds + row * (BN * 2) + (colb ^ (((row >> 2) & 3) << 5))) =
                    f2bfu(a[i][j][r]);
            }
        }
    }
    __syncthreads();
    const int TPR = BN / 8;          // threads per row (16B each)
    const int RPP = 256 / TPR;       // rows per pass
    #pragma unroll
    for (int p = 0; p < BM / RPP; ++p) {
        int row = p * RPP + tid / TPR;
        int cb = (tid % TPR) * 16;
        int pb = cb ^ (((row >> 2) & 3) << 5);
        uint4 v = *reinterpret_cast<const uint4*>(lds + row * (BN * 2) + pb);
        *reinterpret_cast<uint4*>(reinterpret_cast<char*>(C + base + (long)row * N) + cb) = v;
    }
}

// ---------------------------------------------------------------------------
// fp32 -> bf16 convert
// ---------------------------------------------------------------------------
__global__ __launch_bounds__(256) void cvt_k(const float* __restrict__ in,
                                             unsigned short* __restrict__ out, long n4)
{
    long gid = (long)blockIdx.x * 256 + threadIdx.x;
    long stride = (long)gridDim.x * 256;
    for (long i = gid; i < n4; i += stride) {
        float4 v = reinterpret_cast<const float4*>(in)[i];
        ushort4 u;
        u.x = f2bfu(v.x); u.y = f2bfu(v.y); u.z = f2bfu(v.z); u.w = f2bfu(v.w);
        reinterpret_cast<ushort4*>(out)[i] = u;
    }
}

// ---------------------------------------------------------------------------
// transpose-convert fp32 (bz,R,C) -> bf16 (bz,C,R); 64x64 tiles
// ---------------------------------------------------------------------------
__device__ __forceinline__ void tcvt_body(const float* __restrict__ in,
                                          unsigned short* __restrict__ out,
                                          int R, int C, int r0, int c0)
{
    __shared__ float t[64][65];
    int tr = threadIdx.x >> 6;
    int tc = threadIdx.x & 63;
    #pragma unroll
    for (int i = 0; i < 16; ++i) {
        int r = i * 4 + tr;
        t[r][tc] = in[(long)(r0 + r) * C + c0 + tc];
    }
    __syncthreads();
    #pragma unroll
    for (int i = 0; i < 16; ++i) {
        int r = i * 4 + tr;
        out[(long)(c0 + r) * R + r0 + tc] = f2bfu(t[tc][r]);
    }
}

__global__ __launch_bounds__(256) void tcvt_k(const float* __restrict__ in,
                                              unsigned short* __restrict__ out,
                                              int R, int C, long sz)
{
    long base = (long)blockIdx.z * sz;
    tcvt_body(in + base, out + base, R, C, blockIdx.y * 64, blockIdx.x * 64);
}

struct WTArgs {
    const float* src[9];
    unsigned short* dst[9];
    int R[9], C[9];
};
__global__ __launch_bounds__(256) void tcvt_w_k(WTArgs a)
{
    int wgt = blockIdx.y;
    int R = a.R[wgt], C = a.C[wgt];
    int tilesX = C >> 6;
    int tiles = (R >> 6) * tilesX;
    int t = blockIdx.x;
    if (t >= tiles) return;
    tcvt_body(a.src[wgt], a.dst[wgt], R, C, (t / tilesX) * 64, (t % tilesX) * 64);
}

// ---------------------------------------------------------------------------
// Single MFMA bf16 GEMM (bf16 out, coalesced epilogue)
// ---------------------------------------------------------------------------
template<int BM, int BN, int FM, int FN>
__global__ __launch_bounds__(256) void gemm_bt_k(
    const __hip_bfloat16* __restrict__ A, const __hip_bfloat16* __restrict__ Bt,
    const float* __restrict__ bias, __hip_bfloat16* __restrict__ Cb,
    int M, int N, int K, long sA, long sB, long sC)
{
    __shared__ __attribute__((aligned(128))) char lds[(BM + BN) * 128];
    char* AsB = lds;
    char* BsB = lds + BM * 128;

    const long bz = blockIdx.z;
    const __hip_bfloat16* Ab = A + bz * sA;
    const __hip_bfloat16* Bb = Bt + bz * sB;

    const int m0 = blockIdx.y * BM;
    const int n0 = blockIdx.x * BN;
    const int tid  = threadIdx.x;
    const int wave = tid >> 6;
    const int lane = tid & 63;
    const int wm = wave >> 1, wn = wave & 1;

    const int NCH = (BM + BN) / 32;
    const int lr = lane >> 3;
    const int ls = lane & 7;

    f32x4 acc[FM][FN];
    #pragma unroll
    for (int i = 0; i < FM; ++i)
        #pragma unroll
        for (int j = 0; j < FN; ++j)
            acc[i][j] = (f32x4){0.f, 0.f, 0.f, 0.f};

    for (int k0 = 0; k0 < K; k0 += 64) {
        #pragma unroll
        for (int cc = 0; cc < NCH; ++cc) {
            int c = wave * NCH + cc;
            const __hip_bfloat16* src;
            char* ldsb;
            if (c < BM / 8) {
                int r = c * 8 + lr;
                ldsb = AsB + c * 1024;
                src = Ab + ((long)(m0 + r) * K + k0 + ((ls ^ (r & 7)) << 3));
            } else {
                int c2 = c - BM / 8;
                int r = c2 * 8 + lr;
                ldsb = BsB + c2 * 1024;
                src = Bb + ((long)(n0 + r) * K + k0 + ((ls ^ (r & 7)) << 3));
            }
            __builtin_amdgcn_global_load_lds(GLP(src), LDSP(ldsb), 16, 0, 0);
        }
        __syncthreads();

        #pragma unroll
        for (int ksl = 0; ksl < 2; ++ksl) {
            bf16x8 af[FM], bfr[FN];
            #pragma unroll
            for (int i = 0; i < FM; ++i) {
                int row = wm * (FM * 16) + i * 16 + (lane & 15);
                int off = (ksl * 64 + ((lane >> 4) << 4)) ^ ((row & 7) << 4);
                af[i] = *reinterpret_cast<const bf16x8*>(AsB + row * 128 + off);
            }
            #pragma unroll
            for (int j = 0; j < FN; ++j) {
                int row = wn * (FN * 16) + j * 16 + (lane & 15);
                int off = (ksl * 64 + ((lane >> 4) << 4)) ^ ((row & 7) << 4);
                bfr[j] = *reinterpret_cast<const bf16x8*>(BsB + row * 128 + off);
            }
            #pragma unroll
            for (int i = 0; i < FM; ++i)
                #pragma unroll
                for (int j = 0; j < FN; ++j)
                    acc[i][j] = __builtin_amdgcn_mfma_f32_16x16x32_bf16(
                        af[i], bfr[j], acc[i][j], 0, 0, 0);
        }
        __syncthreads();
    }

    const int lc = lane & 15;
    #pragma unroll
    for (int j = 0; j < FN; ++j) {
        int col = n0 + wn * (FN * 16) + j * 16 + lc;
        float bv = bias ? bias[col] : 0.0f;
        #pragma unroll
        for (int i = 0; i < FM; ++i)
            #pragma unroll
            for (int r = 0; r < 4; ++r)
                acc[i][j][r] += bv;
    }
    write_tile<BM, BN, FM, FN>(lds, acc, Cb, bz * sC + (long)m0 * N + n0, N, tid);
}

// ---------------------------------------------------------------------------
// Dual MFMA GEMM + in-register diff reduction + coalesced epilogue:
//   C1 = A1@B1 + bias1 (+resid1 bf16), C2 = A2@B2 + bias2,
//   partial[block] = sum of (C1-C2)^2 (fp32, pre-rounding).
// ---------------------------------------------------------------------------
template<int BM, int BN, int FM, int FN>
__global__ __launch_bounds__(256) void dual_k(
    const __hip_bfloat16* __restrict__ A1, const __hip_bfloat16* __restrict__ B1t,
    const float* __restrict__ bias1, const __hip_bfloat16* __restrict__ resid1,
    const __hip_bfloat16* __restrict__ A2, const __hip_bfloat16* __restrict__ B2t,
    const float* __restrict__ bias2,
    __hip_bfloat16* __restrict__ C1, __hip_bfloat16* __restrict__ C2,
    float* __restrict__ partial,
    int M, int N, int K1, int K2)
{
    __shared__ __attribute__((aligned(128))) char lds[(BM + BN) * 128];
    char* AsB = lds;
    char* BsB = lds + BM * 128;

    const int m0 = blockIdx.y * BM;
    const int n0 = blockIdx.x * BN;
    const int tid  = threadIdx.x;
    const int wave = tid >> 6;
    const int lane = tid & 63;
    const int wm = wave >> 1, wn = wave & 1;

    const int NCH = (BM + BN) / 32;
    const int lr = lane >> 3;
    const int ls = lane & 7;

    f32x4 acc[2][FM][FN];
    #pragma unroll
    for (int p = 0; p < 2; ++p)
        #pragma unroll
        for (int i = 0; i < FM; ++i)
            #pragma unroll
            for (int j = 0; j < FN; ++j)
                acc[p][i][j] = (f32x4){0.f, 0.f, 0.f, 0.f};

    #pragma unroll
    for (int ph = 0; ph < 2; ++ph) {
        const __hip_bfloat16* Ab = ph ? A2 : A1;
        const __hip_bfloat16* Bb = ph ? B2t : B1t;
        const int K = ph ? K2 : K1;

        for (int k0 = 0; k0 < K; k0 += 64) {
            #pragma unroll
            for (int cc = 0; cc < NCH; ++cc) {
                int c = wave * NCH + cc;
                const __hip_bfloat16* src;
                char* ldsb;
                if (c < BM / 8) {
                    int r = c * 8 + lr;
                    ldsb = AsB + c * 1024;
                    src = Ab + ((long)(m0 + r) * K + k0 + ((ls ^ (r & 7)) << 3));
                } else {
                    int c2 = c - BM / 8;
                    int r = c2 * 8 + lr;
                    ldsb = BsB + c2 * 1024;
                    src = Bb + ((long)(n0 + r) * K + k0 + ((ls ^ (r & 7)) << 3));
                }
                __builtin_amdgcn_global_load_lds(GLP(src), LDSP(ldsb), 16, 0, 0);
            }
            __syncthreads();

            #pragma unroll
            for (int ksl = 0; ksl < 2; ++ksl) {
                bf16x8 af[FM], bfr[FN];
                #pragma unroll
                for (int i = 0; i < FM; ++i) {
                    int row = wm * (FM * 16) + i * 16 + (lane & 15);
                    int off = (ksl * 64 + ((lane >> 4) << 4)) ^ ((row & 7) << 4);
                    af[i] = *reinterpret_cast<const bf16x8*>(AsB + row * 128 + off);
                }
                #pragma unroll
                for (int j = 0; j < FN; ++j) {
                    int row = wn * (FN * 16) + j * 16 + (lane & 15);
                    int off = (ksl * 64 + ((lane >> 4) << 4)) ^ ((row & 7) << 4);
                    bfr[j] = *reinterpret_cast<const bf16x8*>(BsB + row * 128 + off);
                }
                #pragma unroll
                for (int i = 0; i < FM; ++i)
                    #pragma unroll
                    for (int j = 0; j < FN; ++j)
                        acc[ph][i][j] = __builtin_amdgcn_mfma_f32_16x16x32_bf16(
                            af[i], bfr[j], acc[ph][i][j], 0, 0, 0);
            }
            __syncthreads();
        }
    }

    // finalize values in registers (bias, resid, diff)
    const int lc  = lane & 15;
    const int lr4 = (lane >> 4) << 2;
    float dsum = 0.f;
    #pragma unroll
    for (int j = 0; j < FN; ++j) {
        int col = n0 + wn * (FN * 16) + j * 16 + lc;
        float b1 = bias1 ? bias1[col] : 0.0f;
        float b2 = bias2 ? bias2[col] : 0.0f;
        #pragma unroll
        for (int i = 0; i < FM; ++i) {
            int row0 = m0 + wm * (FM * 16) + i * 16 + lr4;
            #pragma unroll
            for (int r = 0; r < 4; ++r) {
                float v1 = acc[0][i][j][r] + b1;
                if (resid1) v1 += __bfloat162float(resid1[(long)(row0 + r) * N + col]);
                float v2 = acc[1][i][j][r] + b2;
                acc[0][i][j][r] = v1;
                acc[1][i][j][r] = v2;
                float d = v1 - v2;
                dsum += d * d;
            }
        }
    }

    // block diff reduction (staging LDS is dead; all waves past final sync)
    float* red = (float*)lds;
    red[tid] = dsum;
    __syncthreads();
    for (int o = 128; o > 0; o >>= 1) {
        if (tid < o) red[tid] += red[tid + o];
        __syncthreads();
    }
    if (tid == 0) partial[blockIdx.y * gridDim.x + blockIdx.x] = red[0];

    write_tile<BM, BN, FM, FN>(lds, acc[0], C1, (long)m0 * N + n0, N, tid);
    write_tile<BM, BN, FM, FN>(lds, acc[1], C2, (long)m0 * N + n0, N, tid);
}

// ---------------------------------------------------------------------------
// th = sigmoid(sum(partial)/n)
// ---------------------------------------------------------------------------
__global__ __launch_bounds__(256) void diff_final_k(
    const float* __restrict__ partial, int np, float* __restrict__ th_out, float inv_n)
{
    float s = 0.f;
    for (int i = threadIdx.x; i < np; i += 256) s += partial[i];
    __shared__ float sm[256];
    sm[threadIdx.x] = s;
    __syncthreads();
    for (int o = 128; o > 0; o >>= 1) {
        if (threadIdx.x < o) sm[threadIdx.x] += sm[threadIdx.x + o];
        __syncthreads();
    }
    if (threadIdx.x == 0) {
        float d = sm[0] * inv_n;
        th_out[0] = 1.f / (1.f + expf(-d));
    }
}

// ---------------------------------------------------------------------------
// wavelet coeff
// ---------------------------------------------------------------------------
__global__ void coeff_k(const float* __restrict__ logits, const float* __restrict__ gumb,
                        const float* __restrict__ Wnl, float* __restrict__ coeff)
{
    int f = threadIdx.x;
    float l0 = logits[0] + gumb[f * 3 + 0];
    float l1 = logits[1] + gumb[f * 3 + 1];
    float l2 = logits[2] + gumb[f * 3 + 2];
    int bl = 0;
    float bv = l0;
    if (l1 > bv) { bv = l1; bl = 1; }
    if (l2 > bv) { bv = l2; bl = 2; }
    float s = 0.f;
    #pragma unroll
    for (int t = 0; t < 8; ++t) s += Wnl[f * 8 + t] * PAT[bl][t];
    coeff[f] = s;
}

// ---------------------------------------------------------------------------
// fused mix + wavelet scale/bias
// ---------------------------------------------------------------------------
__global__ __launch_bounds__(256) void mixagg_k(
    const unsigned short* __restrict__ h, const unsigned short* __restrict__ r,
    const float* __restrict__ th_p, const float* __restrict__ coeff,
    const float* __restrict__ bnl,
    unsigned short* __restrict__ agg, unsigned short* __restrict__ mout,
    long n8, int F8)
{
    const float th = th_p[0];
    const float om = 1.f - th;
    long gid = (long)blockIdx.x * 256 + threadIdx.x;
    long stride = (long)gridDim.x * 256;
    for (long i = gid; i < n8; i += stride) {
        uint4 hv = reinterpret_cast<const uint4*>(h)[i];
        uint4 rv = reinterpret_cast<const uint4*>(r)[i];
        int f0 = (int)(i % F8) * 8;
        float4 ca = *reinterpret_cast<const float4*>(coeff + f0);
        float4 cb = *reinterpret_cast<const float4*>(coeff + f0 + 4);
        float4 ba = *reinterpret_cast<const float4*>(bnl + f0);
        float4 bb = *reinterpret_cast<const float4*>(bnl + f0 + 4);
        float c[8] = {ca.x, ca.y, ca.z, ca.w, cb.x, cb.y, cb.z, cb.w};
        float b[8] = {ba.x, ba.y, ba.z, ba.w, bb.x, bb.y, bb.z, bb.w};
        unsigned int hw[4] = {hv.x, hv.y, hv.z, hv.w};
        unsigned int rw[4] = {rv.x, rv.y, rv.z, rv.w};
        unsigned int ao[4], mo[4];
        #pragma unroll
        for (int q = 0; q < 4; ++q) {
            float h0 = bf2f((unsigned short)(hw[q] & 0xffff));
            float h1 = bf2f((unsigned short)(hw[q] >> 16));
            float r0 = bf2f((unsigned short)(rw[q] & 0xffff));
            float r1 = bf2f((unsigned short)(rw[q] >> 16));
            float m0 = th * h0 + om * r0;
            float m1 = th * h1 + om * r1;
            float a0 = m0 * c[q * 2] + b[q * 2];
            float a1 = m1 * c[q * 2 + 1] + b[q * 2 + 1];
            ao[q] = (unsigned int)f2bfu(a0) | ((unsigned int)f2bfu(a1) << 16);
            mo[q] = (unsigned int)f2bfu(m0) | ((unsigned int)f2bfu(m1) << 16);
        }
        reinterpret_cast<uint4*>(agg)[i] = make_uint4(ao[0], ao[1], ao[2], ao[3]);
        if (mout)
            reinterpret_cast<uint4*>(mout)[i] = make_uint4(mo[0], mo[1], mo[2], mo[3]);
    }
}

// ---------------------------------------------------------------------------
// fused mix + batched transpose
// ---------------------------------------------------------------------------
__global__ __launch_bounds__(256) void mixT_k(
    const unsigned short* __restrict__ h, const unsigned short* __restrict__ r,
    const float* __restrict__ th_p,
    unsigned short* __restrict__ xw, unsigned short* __restrict__ xwT)
{
    const float th = th_p[0];
    const float om = 1.f - th;
    __shared__ float t[64][65];
    const long base = (long)blockIdx.z * NN * HH;
    const int r0 = blockIdx.y * 64;
    const int c0 = blockIdx.x * 64;
    const int tr = threadIdx.x >> 6;
    const int tc = threadIdx.x & 63;
    #pragma unroll
    for (int i = 0; i < 16; ++i) {
        int rr = i * 4 + tr;
        long idx = base + (long)(r0 + rr) * HH + c0 + tc;
        float m = th * bf2f(h[idx]) + om * bf2f(r[idx]);
        xw[idx] = f2bfu(m);
        t[rr][tc] = m;
    }
    __syncthreads();
    #pragma unroll
    for (int i = 0; i < 16; ++i) {
        int rr = i * 4 + tr;
        xwT[base + (long)(c0 + rr) * NN + r0 + tc] = f2bfu(t[tc][rr]);
    }
}

// ---------------------------------------------------------------------------
// final mix: out = th*h + (1-th)*r, fp32 out
// ---------------------------------------------------------------------------
__global__ __launch_bounds__(256) void mixfinal_k(
    const unsigned short* __restrict__ h, const unsigned short* __restrict__ r,
    const float* __restrict__ th_p, float* __restrict__ out, long n4)
{
    const float th = th_p[0];
    const float om = 1.f - th;
    long gid = (long)blockIdx.x * 256 + threadIdx.x;
    long stride = (long)gridDim.x * 256;
    for (long i = gid; i < n4; i += stride) {
        ushort4 hv = reinterpret_cast<const ushort4*>(h)[i];
        ushort4 rv = reinterpret_cast<const ushort4*>(r)[i];
        float4 o;
        o.x = th * bf2f(hv.x) + om * bf2f(rv.x);
        o.y = th * bf2f(hv.y) + om * bf2f(rv.y);
        o.z = th * bf2f(hv.z) + om * bf2f(rv.z);
        o.w = th * bf2f(hv.w) + om * bf2f(rv.w);
        reinterpret_cast<float4*>(out)[i] = o;
    }
}

// ---------------------------------------------------------------------------
extern "C" void kernel_launch(void* const* d_in, const int* in_sizes, int n_in,
                              void* d_out, int out_size, void* d_ws, size_t ws_size,
                              hipStream_t stream)
{
    const float* x       = (const float*)d_in[0];
    const float* adj     = (const float*)d_in[1];
    const float* Wres    = (const float*)d_in[2];
    const float* bres    = (const float*)d_in[3];
    const float* Wg0     = (const float*)d_in[4];
    const float* bg0     = (const float*)d_in[5];
    const float* Wrg0    = (const float*)d_in[6];
    const float* brg0    = (const float*)d_in[7];
    const float* logits0 = (const float*)d_in[8];
    const float* gumb0   = (const float*)d_in[9];
    const float* Wnl0    = (const float*)d_in[10];
    const float* bnl0    = (const float*)d_in[11];
    const float* Wwo0    = (const float*)d_in[12];
    const float* bwo0    = (const float*)d_in[13];
    const float* Wrw0    = (const float*)d_in[14];
    const float* brw0    = (const float*)d_in[15];
    const float* Wg1     = (const float*)d_in[16];
    const float* bg1     = (const float*)d_in[17];
    const float* Wrg1    = (const float*)d_in[18];
    const float* brg1    = (const float*)d_in[19];
    const float* logits1 = (const float*)d_in[20];
    const float* gumb1   = (const float*)d_in[21];
    const float* Wnl1    = (const float*)d_in[22];
    const float* bnl1    = (const float*)d_in[23];
    const float* Wwo1    = (const float*)d_in[24];
    const float* bwo1    = (const float*)d_in[25];
    const float* Wrw1    = (const float*)d_in[26];
    const float* brw1    = (const float*)d_in[27];

    float* out = (float*)d_out;

    // ---- workspace ----
    char* w = (char*)d_ws;
    auto alloc = [&](long bytes) { char* p = w; w += (bytes + 255) & ~255L; return p; };
    const long SLOT = (long)BNR * HH * 2;                 // 32 MB
    char* pool = alloc(6 * SLOT);                         // 192 MB
    __hip_bfloat16* Rbf  = (__hip_bfloat16*)alloc((long)BNR * DOUT * 2); // 8 MB
    __hip_bfloat16* adjb = (__hip_bfloat16*)alloc((long)NN * NN * 2);
    __hip_bfloat16* WT   = (__hip_bfloat16*)alloc(221184L * 2);
    float* partial = (float*)alloc(4096 * 4);
    float* th_s    = (float*)alloc(16);
    float* c0      = (float*)alloc(256 * 4);
    float* c1      = (float*)alloc(256 * 4);

    auto S = [&](int i) { return pool + (long)i * SLOT; };
    __hip_bfloat16* xbf  = (__hip_bfloat16*)S(1);
    __hip_bfloat16* xT   = (__hip_bfloat16*)(S(1) + (long)BNR * DIN * 2);
    __hip_bfloat16* T0   = (__hip_bfloat16*)S(0);
    __hip_bfloat16* xg   = (__hip_bfloat16*)S(2);
    __hip_bfloat16* rg   = (__hip_bfloat16*)S(3);
    __hip_bfloat16* Agg0 = (__hip_bfloat16*)S(0);
    __hip_bfloat16* m0   = (__hip_bfloat16*)S(1);
    __hip_bfloat16* xwr  = (__hip_bfloat16*)S(2);   // xw_raw
    __hip_bfloat16* rw0  = (__hip_bfloat16*)S(3);
    __hip_bfloat16* xw   = (__hip_bfloat16*)S(0);
    __hip_bfloat16* xwT  = (__hip_bfloat16*)S(1);
    __hip_bfloat16* T1   = (__hip_bfloat16*)S(2);
    __hip_bfloat16* xg1  = (__hip_bfloat16*)S(1);
    __hip_bfloat16* rg1  = (__hip_bfloat16*)S(3);
    __hip_bfloat16* Agg1 = (__hip_bfloat16*)S(2);
    __hip_bfloat16* orw  = (__hip_bfloat16*)S(1);   // o_raw
    __hip_bfloat16* rw1  = (__hip_bfloat16*)S(3);

    __hip_bfloat16* WresT = WT;             // 64x64
    __hip_bfloat16* Wg0T  = WT + 4096;      // 256x64
    __hip_bfloat16* Wrg0T = WT + 20480;     // 256x64
    __hip_bfloat16* Wwo0T = WT + 36864;     // 256x256
    __hip_bfloat16* Wrw0T = WT + 102400;    // 256x64
    __hip_bfloat16* Wg1T  = WT + 118784;    // 256x256
    __hip_bfloat16* Wrg1T = WT + 184320;    // 256x64
    __hip_bfloat16* Wwo1T = WT + 200704;    // 64x256
    __hip_bfloat16* Wrw1T = WT + 217088;    // 64x64

    const dim3 blk(256);
    const float invH = 1.0f / ((float)BNR * HH);
    const float invD = 1.0f / ((float)BNR * DOUT);

    // ---- conversions ----
    hipLaunchKernelGGL(cvt_k, dim3(2048), blk, 0, stream, x, (unsigned short*)xbf, (long)BNR * DIN / 4);
    hipLaunchKernelGGL(cvt_k, dim3(256), blk, 0, stream, adj, (unsigned short*)adjb, (long)NN * NN / 4);
    hipLaunchKernelGGL(tcvt_k, dim3(1, 8, 128), blk, 0, stream, x, (unsigned short*)xT, NN, DIN, (long)NN * DIN);
    WTArgs wa;
    wa.src[0] = Wres; wa.dst[0] = (unsigned short*)WresT; wa.R[0] = 64;  wa.C[0] = 64;
    wa.src[1] = Wg0;  wa.dst[1] = (unsigned short*)Wg0T;  wa.R[1] = 64;  wa.C[1] = 256;
    wa.src[2] = Wrg0; wa.dst[2] = (unsigned short*)Wrg0T; wa.R[2] = 64;  wa.C[2] = 256;
    wa.src[3] = Wwo0; wa.dst[3] = (unsigned short*)Wwo0T; wa.R[3] = 256; wa.C[3] = 256;
    wa.src[4] = Wrw0; wa.dst[4] = (unsigned short*)Wrw0T; wa.R[4] = 64;  wa.C[4] = 256;
    wa.src[5] = Wg1;  wa.dst[5] = (unsigned short*)Wg1T;  wa.R[5] = 256; wa.C[5] = 256;
    wa.src[6] = Wrg1; wa.dst[6] = (unsigned short*)Wrg1T; wa.R[6] = 64;  wa.C[6] = 256;
    wa.src[7] = Wwo1; wa.dst[7] = (unsigned short*)Wwo1T; wa.R[7] = 256; wa.C[7] = 64;
    wa.src[8] = Wrw1; wa.dst[8] = (unsigned short*)Wrw1T; wa.R[8] = 64;  wa.C[8] = 64;
    hipLaunchKernelGGL(tcvt_w_k, dim3(16, 9), blk, 0, stream, wa);

    hipLaunchKernelGGL(coeff_k, dim3(1), dim3(256), 0, stream, logits0, gumb0, Wnl0, c0);
    hipLaunchKernelGGL(coeff_k, dim3(1), dim3(256), 0, stream, logits1, gumb1, Wnl1, c1);

    // res = x @ Wres + bres
    hipLaunchKernelGGL((gemm_bt_k<128, 64, 4, 2>), dim3(1, BNR / 128, 1), blk, 0, stream,
                       xbf, WresT, bres, Rbf, BNR, DOUT, DIN, 0, 0, 0);

    // T0 = adj @ x (batched)
    hipLaunchKernelGGL((gemm_bt_k<128, 64, 4, 2>), dim3(1, 4, BB), blk, 0, stream,
                       adjb, xT, nullptr, T0, NN, DIN, NN, 0, (long)DIN * NN, (long)NN * DIN);

    // dual0: xg = T0@Wg0+bg0 ; rg = Rbf@Wrg0+brg0 (+diff)
    hipLaunchKernelGGL((dual_k<64, 128, 2, 4>), dim3(2, BNR / 64), blk, 0, stream,
                       T0, Wg0T, bg0, (const __hip_bfloat16*)nullptr,
                       Rbf, Wrg0T, brg0, xg, rg, partial, BNR, HH, DIN, DOUT);
    hipLaunchKernelGGL(diff_final_k, dim3(1), blk, 0, stream, partial, 2048, th_s + 0, invH);

    hipLaunchKernelGGL(mixagg_k, dim3(2048), blk, 0, stream,
                       (const unsigned short*)xg, (const unsigned short*)rg, th_s + 0, c0, bnl0,
                       (unsigned short*)Agg0, (unsigned short*)m0, (long)BNR * HH / 8, HH / 8);

    // dual_w0: xw_raw = Agg0@Wwo0+bwo0+m0 ; rw0 = Rbf@Wrw0+brw0 (+diff)
    hipLaunchKernelGGL((dual_k<64, 128, 2, 4>), dim3(2, BNR / 64), blk, 0, stream,
                       Agg0, Wwo0T, bwo0, m0,
                       Rbf, Wrw0T, brw0, xwr, rw0, partial, BNR, HH, HH, DOUT);
    hipLaunchKernelGGL(diff_final_k, dim3(1), blk, 0, stream, partial, 2048, th_s + 1, invH);

    hipLaunchKernelGGL(mixT_k, dim3(4, 8, BB), blk, 0, stream,
                       (const unsigned short*)xwr, (const unsigned short*)rw0, th_s + 1,
                       (unsigned short*)xw, (unsigned short*)xwT);

    // T1 = adj @ xw (batched)
    hipLaunchKernelGGL((gemm_bt_k<128, 128, 4, 4>), dim3(2, 4, BB), blk, 0, stream,
                       adjb, xwT, nullptr, T1, NN, HH, NN, 0, (long)HH * NN, (long)NN * HH);

    // dual1: xg1 = T1@Wg1+bg1+xw ; rg1 = Rbf@Wrg1+brg1 (+diff)
    hipLaunchKernelGGL((dual_k<64, 128, 2, 4>), dim3(2, BNR / 64), blk, 0, stream,
                       T1, Wg1T, bg1, xw,
                       Rbf, Wrg1T, brg1, xg1, rg1, partial, BNR, HH, HH, DOUT);
    hipLaunchKernelGGL(diff_final_k, dim3(1), blk, 0, stream, partial, 2048, th_s + 2, invH);

    hipLaunchKernelGGL(mixagg_k, dim3(2048), blk, 0, stream,
                       (const unsigned short*)xg1, (const unsigned short*)rg1, th_s + 2, c1, bnl1,
                       (unsigned short*)Agg1, (unsigned short*)nullptr, (long)BNR * HH / 8, HH / 8);

    // dual_out: o_raw = Agg1@Wwo1+bwo1 ; rw1 = Rbf@Wrw1+brw1 (+diff)
    hipLaunchKernelGGL((dual_k<64, 64, 2, 2>), dim3(1, BNR / 64), blk, 0, stream,
                       Agg1, Wwo1T, bwo1, (const __hip_bfloat16*)nullptr,
                       Rbf, Wrw1T, brw1, orw, rw1, partial, BNR, DOUT, HH, DIN);
    hipLaunchKernelGGL(diff_final_k, dim3(1), blk, 0, stream, partial, 1024, th_s + 3, invD);

    hipLaunchKernelGGL(mixfinal_k, dim3(2048), blk, 0, stream,
                       (const unsigned short*)orw, (const unsigned short*)rw1, th_s + 3,
                       out, (long)BNR * DOUT / 4);
}